// Round 6
// baseline (1006.615 us; speedup 1.0000x reference)
//
#include <hip/hip_runtime.h>
#include <hip/hip_bf16.h>
#include <cfloat>
#include <math.h>

typedef __bf16 bf16;
typedef __bf16 bf16x4 __attribute__((ext_vector_type(4)));
typedef __bf16 bf16x8 __attribute__((ext_vector_type(8)));
typedef float  floatx4 __attribute__((ext_vector_type(4)));
typedef float  floatx2 __attribute__((ext_vector_type(2)));

#define SEQ 2048
#define DM  1024
#define NP  2048
#define CAP (1 << 20)
#define MARGIN 0.5f

// ------- mask dtype detect + expand + order-preserving compaction + inits ----
__global__ __launch_bounds__(256) void mask_prep(
    const void* __restrict__ mraw, int* __restrict__ maskw,
    int* __restrict__ midx, int* __restrict__ mc,
    int* __restrict__ gcount, float* __restrict__ sums,
    unsigned long long* __restrict__ keys) {
  __shared__ int flags;
  __shared__ int lmask[2048];
  int t = threadIdx.x;
  if (t == 0) flags = 0;
  __syncthreads();
  const unsigned short* u16 = (const unsigned short*)mraw;
  const unsigned* u32 = (const unsigned*)mraw;
  int f = 0;
  for (int i = t; i < 1024; i += 256) {
    unsigned short v = u16[i];
    if (v != 0 && v != 0x3F80u) f |= 1;
    if ((i & 1) == 0 && v == 0x3F80u) f |= 2;
  }
  for (int i = t; i < 512; i += 256)
    if (u32[i] > 1u) f |= 4;
  if (f) atomicOr(&flags, f);
  // workspace inits (replaces hipMemsetAsync calls)
  if (t == 0) *gcount = 0;
  for (int i = t; i < 2048; i += 256) sums[i] = 0.f;
  for (int i = t; i < 16 * SEQ; i += 256) keys[i] = ~0ULL;
  __syncthreads();
  int fl = flags;
  int mode;
  if (!(fl & 1)) mode = (fl & 2) ? 2 : 3;
  else           mode = (fl & 4) ? 1 : 0;
  for (int s = t; s < SEQ; s += 256) {
    int m;
    if (mode == 0)      m = (((const int*)mraw)[s] != 0);
    else if (mode == 1) m = (((const unsigned char*)mraw)[s] != 0);
    else if (mode == 2) m = (u16[s] != 0);
    else                m = (((const float*)mraw)[s] != 0.0f);
    maskw[s] = m; lmask[s] = m;
  }
  __syncthreads();
  if (t < 64) {                      // wave-0 ballot compaction, order-preserving
    int base = 0;
    for (int c = 0; c < 32; c++) {
      int s = c * 64 + t;
      bool m = lmask[s] != 0;
      unsigned long long bal = __ballot(m);
      if (m) midx[base + __popcll(bal & ((1ULL << t) - 1ULL))] = s;
      base += __popcll(bal);
    }
    if (t == 0) *mc = base;
  }
}

// ---------------- Q/K projection on COMPACTED masked rows, fp64 VALU --------
// 64m x 128n tile, 4x8 per thread, no LDS (A broadcast / B cacheline reads).
// Ascending-k fp64 FMA chain == rounds 2/4/5 PASS numerics, rows just gathered.
// Outputs compacted fp32 [16][2048cap][128] + bf16 copy.
__global__ __launch_bounds__(256, 2) void proj_qk(
    const float* __restrict__ X,
    const float* __restrict__ Wq, const float* __restrict__ Wk,
    const float* __restrict__ bq, const float* __restrict__ bk,
    const int* __restrict__ midx, const int* __restrict__ mc,
    float* __restrict__ qo, float* __restrict__ ko,
    bf16* __restrict__ qbo, bf16* __restrict__ kbo) {
  int mcv = *mc;
  int mb = blockIdx.x;
  if (mb * 64 >= mcv) return;
  int z = blockIdx.z;
  const float* W   = z ? Wk : Wq;
  const float* bia = z ? bk : bq;
  float*       out = z ? ko : qo;
  bf16*        outb= z ? kbo : qbo;
  int n0 = blockIdx.y * 128;
  int t = threadIdx.x, g = t >> 4, tn = t & 15;
  const float* xr[4];
  int crow[4];
  #pragma unroll
  for (int i = 0; i < 4; i++) {
    int c = mb * 64 + g + 16 * i;
    crow[i] = c;
    int cc = c < mcv ? c : (mcv - 1);
    xr[i] = X + (size_t)midx[cc] * DM;
  }
  const float* wbase = W + n0 + tn * 8;
  double acc[4][8];
  #pragma unroll
  for (int i = 0; i < 4; i++)
    #pragma unroll
    for (int j = 0; j < 8; j++) acc[i][j] = 0.0;

  for (int kt = 0; kt < DM; kt += 4) {
    floatx4 a4[4], b0[4], b1[4];
    #pragma unroll
    for (int i = 0; i < 4; i++) a4[i] = *(const floatx4*)(xr[i] + kt);
    #pragma unroll
    for (int u = 0; u < 4; u++) {
      b0[u] = *(const floatx4*)(wbase + (size_t)(kt + u) * NP);
      b1[u] = *(const floatx4*)(wbase + (size_t)(kt + u) * NP + 4);
    }
    #pragma unroll
    for (int u = 0; u < 4; u++) {       // ascending k within the quad
      double bv[8];
      #pragma unroll
      for (int j = 0; j < 4; j++) { bv[j] = (double)b0[u][j]; bv[4 + j] = (double)b1[u][j]; }
      #pragma unroll
      for (int i = 0; i < 4; i++) {
        double av = (double)a4[i][u];
        #pragma unroll
        for (int j = 0; j < 8; j++)
          acc[i][j] = fma(av, bv[j], acc[i][j]);
      }
    }
  }
  int head = n0 >> 7;
  #pragma unroll
  for (int i = 0; i < 4; i++) {
    float vals[8]; bf16 bvals[8];
    size_t base = ((size_t)head * SEQ + crow[i]) * 128 + tn * 8;
    #pragma unroll
    for (int j = 0; j < 8; j++) {
      float v = (float)(acc[i][j] + (double)bia[n0 + tn * 8 + j]);
      vals[j] = v; bvals[j] = (bf16)v;
    }
    *(floatx4*)(out + base)     = *(floatx4*)&vals[0];
    *(floatx4*)(out + base + 4) = *(floatx4*)&vals[4];
    *(bf16x8*)(outb + base)     = *(bf16x8*)&bvals[0];
  }
}

// -------- V projection via bf16 MFMA + fused column-sum (for the mean) ------
__global__ __launch_bounds__(256) void proj_v_mfma(
    const float* __restrict__ X, const float* __restrict__ W,
    const float* __restrict__ bia, float* __restrict__ out,
    float* __restrict__ sums) {
  __shared__ alignas(16) bf16 As[128][40];
  __shared__ alignas(16) bf16 Bs[128][40];
  __shared__ float colsum[128];
  int ms = blockIdx.x * 128, ns = blockIdx.y * 128;
  int t = threadIdx.x, w = t >> 6, lane = t & 63, l15 = lane & 15, qd = lane >> 4;
  int wm = (w >> 1) * 64, wn = (w & 1) * 64;
  int amr = t >> 1, akb = (t & 1) * 16;
  int bkr = t >> 3, bnb = (t & 7) * 16;
  if (t < 128) colsum[t] = 0.f;
  floatx4 acc[4][4];
  for (int i = 0; i < 4; i++)
    for (int j = 0; j < 4; j++) acc[i][j] = (floatx4){0.f, 0.f, 0.f, 0.f};

  for (int kt = 0; kt < DM; kt += 32) {
    floatx4 xa[4], wv[4];
    for (int u = 0; u < 4; u++)
      xa[u] = *(const floatx4*)(X + (size_t)(ms + amr) * DM + kt + akb + u * 4);
    for (int u = 0; u < 4; u++)
      wv[u] = *(const floatx4*)(W + (size_t)(kt + bkr) * NP + ns + bnb + u * 4);
    __syncthreads();
    {
      bf16x8 p0, p1;
      for (int j = 0; j < 4; j++) { p0[j] = (bf16)xa[0][j]; p0[4 + j] = (bf16)xa[1][j]; }
      for (int j = 0; j < 4; j++) { p1[j] = (bf16)xa[2][j]; p1[4 + j] = (bf16)xa[3][j]; }
      *(bf16x8*)&As[amr][akb]     = p0;
      *(bf16x8*)&As[amr][akb + 8] = p1;
    }
    for (int u = 0; u < 4; u++)
      for (int j = 0; j < 4; j++)
        Bs[bnb + u * 4 + j][bkr] = (bf16)wv[u][j];
    __syncthreads();
    bf16x8 af[4], bfr[4];
    for (int i = 0; i < 4; i++) af[i]  = *(const bf16x8*)&As[wm + i * 16 + l15][qd * 8];
    for (int j = 0; j < 4; j++) bfr[j] = *(const bf16x8*)&Bs[wn + j * 16 + l15][qd * 8];
    for (int i = 0; i < 4; i++)
      for (int j = 0; j < 4; j++)
        acc[i][j] = __builtin_amdgcn_mfma_f32_16x16x32_bf16(af[i], bfr[j], acc[i][j], 0, 0, 0);
  }
  float part[4] = {0.f, 0.f, 0.f, 0.f};
  for (int i = 0; i < 4; i++) {
    for (int j = 0; j < 4; j++) {
      int n = ns + wn + j * 16 + l15;
      float bb = bia[n];
      for (int r = 0; r < 4; r++) {
        int m = ms + wm + i * 16 + qd * 4 + r;
        float v = acc[i][j][r] + bb;
        out[(size_t)m * NP + n] = v;
        part[j] += v;
      }
    }
  }
  for (int j = 0; j < 4; j++)
    atomicAdd(&colsum[wn + j * 16 + l15], part[j]);
  __syncthreads();
  if (t < 128) atomicAdd(&sums[ns + t], colsum[t]);
}

// ------- approx scores on compacted rows (bf16 MFMA), candidate collect -----
__global__ __launch_bounds__(256) void scores_cand(
    const bf16* __restrict__ Qb, const bf16* __restrict__ Kb,
    const int* __restrict__ mc,
    unsigned* __restrict__ cand, int* __restrict__ gcount) {
  int mcv = *mc;
  int h = blockIdx.x, s0 = blockIdx.y * 64;
  if (s0 >= mcv) return;
  __shared__ float lmin[64][4];
  __shared__ float fmin[64];
  int t = threadIdx.x, w = t >> 6, lane = t & 63, l15 = lane & 15, qd = lane >> 4;
  const bf16* Qh = Qb + (size_t)h * SEQ * 128;
  const bf16* Kh = Kb + (size_t)h * SEQ * 128;

  bf16x8 af[4][4];
  for (int ksp = 0; ksp < 4; ksp++)
    for (int i = 0; i < 4; i++)
      af[ksp][i] = *(const bf16x8*)(Qh + (size_t)(s0 + i * 16 + l15) * 128 + ksp * 32 + qd * 8);

  int nt = (mcv + 63) >> 6;
  float rmin[4][4];
  for (int i = 0; i < 4; i++)
    for (int r = 0; r < 4; r++) rmin[i][r] = INFINITY;

  for (int tt = 0; tt < nt; tt++) {
    int t0 = tt * 64;
    floatx4 acc[4];
    for (int i = 0; i < 4; i++) acc[i] = (floatx4){0.f, 0.f, 0.f, 0.f};
    for (int ksp = 0; ksp < 4; ksp++) {
      bf16x8 bfr = *(const bf16x8*)(Kh + (size_t)(t0 + w * 16 + l15) * 128 + ksp * 32 + qd * 8);
      for (int i = 0; i < 4; i++)
        acc[i] = __builtin_amdgcn_mfma_f32_16x16x32_bf16(af[ksp][i], bfr, acc[i], 0, 0, 0);
    }
    bool okc = (t0 + w * 16 + l15) < mcv;
    for (int i = 0; i < 4; i++)
      for (int r = 0; r < 4; r++)
        rmin[i][r] = fminf(rmin[i][r], okc ? acc[i][r] : INFINITY);
  }
  for (int m = 1; m < 16; m <<= 1)
    for (int i = 0; i < 4; i++)
      for (int r = 0; r < 4; r++)
        rmin[i][r] = fminf(rmin[i][r], __shfl_xor(rmin[i][r], m));
  if (l15 == 0)
    for (int i = 0; i < 4; i++)
      for (int r = 0; r < 4; r++)
        lmin[i * 16 + qd * 4 + r][w] = rmin[i][r];
  __syncthreads();
  if (t < 64)
    fmin[t] = fminf(fminf(lmin[t][0], lmin[t][1]), fminf(lmin[t][2], lmin[t][3])) + MARGIN;
  __syncthreads();

  for (int tt = 0; tt < nt; tt++) {
    int t0 = tt * 64;
    floatx4 acc[4];
    for (int i = 0; i < 4; i++) acc[i] = (floatx4){0.f, 0.f, 0.f, 0.f};
    for (int ksp = 0; ksp < 4; ksp++) {
      bf16x8 bfr = *(const bf16x8*)(Kh + (size_t)(t0 + w * 16 + l15) * 128 + ksp * 32 + qd * 8);
      for (int i = 0; i < 4; i++)
        acc[i] = __builtin_amdgcn_mfma_f32_16x16x32_bf16(af[ksp][i], bfr, acc[i], 0, 0, 0);
    }
    int tg = t0 + w * 16 + l15;
    if (tg < mcv) {
      for (int i = 0; i < 4; i++)
        for (int r = 0; r < 4; r++) {
          int row = s0 + i * 16 + qd * 4 + r;
          if (row < mcv && acc[i][r] <= fmin[i * 16 + qd * 4 + r]) {
            int pos = atomicAdd(gcount, 1);
            if (pos < CAP)
              cand[pos] = ((unsigned)h << 22) | ((unsigned)row << 11) | (unsigned)tg;
          }
        }
    }
  }
}

// ---------------- fp64 exact rescore (compacted rows), atomicMin key --------
__global__ __launch_bounds__(256) void rescore(
    const float* __restrict__ Q, const float* __restrict__ K,
    const int* __restrict__ midx,
    const unsigned* __restrict__ cand, const int* __restrict__ gcount,
    unsigned long long* __restrict__ keys) {
  int wid  = (blockIdx.x * 256 + threadIdx.x) >> 6;
  int lane = threadIdx.x & 63;
  int nw = gridDim.x * 4;
  int n = *gcount; if (n > CAP) n = CAP;
  for (int c = wid; c < n; c += nw) {
    unsigned u = cand[c];
    int h = u >> 22, cs = (u >> 11) & 2047, ct = u & 2047;
    floatx2 qv = *(const floatx2*)(Q + ((size_t)h * SEQ + cs) * 128 + lane * 2);
    floatx2 kv = *(const floatx2*)(K + ((size_t)h * SEQ + ct) * 128 + lane * 2);
    double d = (double)qv[0] * (double)kv[0] + (double)qv[1] * (double)kv[1];
    for (int off = 32; off; off >>= 1) d += __shfl_down(d, off);
    if (lane == 0) {
      int sorig = midx[cs], torig = midx[ct];
      long long b = __double_as_longlong(d);
      unsigned long long ub = (b >= 0) ? ((unsigned long long)b | 0x8000000000000000ULL)
                                       : ~(unsigned long long)b;
      unsigned long long key = (ub & ~2047ULL) | (unsigned long long)torig;
      atomicMin(&keys[(size_t)h * SEQ + sorig], key);
    }
  }
}

// ---------------- gather / mean, fp32 out ----------------
__global__ __launch_bounds__(256) void assemble(
    const float* __restrict__ V, const float* __restrict__ sums,
    const int* __restrict__ mask, const unsigned long long* __restrict__ keys,
    float* __restrict__ out) {
  int idx = blockIdx.x * 256 + threadIdx.x;
  int s = idx >> 11, n = idx & 2047, h = n >> 7;
  float val;
  if (mask[s]) {
    int tt = (int)(keys[(size_t)h * SEQ + s] & 2047ULL);
    val = V[(size_t)tt * NP + n];
  } else {
    val = sums[n] * (1.0f / 2048.0f);
  }
  out[idx] = val;
}

extern "C" void kernel_launch(void* const* d_in, const int* in_sizes, int n_in,
                              void* d_out, int out_size, void* d_ws, size_t ws_size,
                              hipStream_t stream) {
  (void)in_sizes; (void)n_in; (void)out_size; (void)ws_size;
  const float* X    = (const float*)d_in[0];
  const void*  mraw = d_in[1];
  const float* Wq   = (const float*)d_in[2];
  const float* bq   = (const float*)d_in[3];
  const float* Wk   = (const float*)d_in[4];
  const float* bk   = (const float*)d_in[5];
  const float* Wv   = (const float*)d_in[6];
  const float* bv   = (const float*)d_in[7];

  char* ws = (char*)d_ws;
  float* qf  = (float*)ws;                                  // 16MB compacted [16][2048][128]
  float* kf  = (float*)(ws + ((size_t)16 << 20));           // 16MB
  float* vf  = (float*)(ws + ((size_t)32 << 20));           // 16MB [2048][2048]
  bf16*  qbf = (bf16*) (ws + ((size_t)48 << 20));           // 8MB
  bf16*  kbf = (bf16*) (ws + ((size_t)56 << 20));           // 8MB
  unsigned* cand = (unsigned*)(ws + ((size_t)64 << 20));    // 4MB
  char* misc = ws + ((size_t)68 << 20);
  int*   maskw  = (int*)misc;                               // 8KB
  int*   midx   = (int*)(misc + (8 << 10));                 // 8KB
  int*   mc     = (int*)(misc + (16 << 10));                // 4B
  int*   gcount = (int*)(misc + (16 << 10) + 64);           // 4B
  float* sums   = (float*)(misc + (32 << 10));              // 8KB
  unsigned long long* keys = (unsigned long long*)(misc + (64 << 10)); // 256KB
  float* out = (float*)d_out;

  mask_prep<<<1, 256, 0, stream>>>(mraw, maskw, midx, mc, gcount, sums, keys);
  proj_qk<<<dim3(32, 16, 2), 256, 0, stream>>>(X, Wq, Wk, bq, bk, midx, mc, qf, kf, qbf, kbf);
  proj_v_mfma<<<dim3(16, 16), 256, 0, stream>>>(X, Wv, bv, vf, sums);
  scores_cand<<<dim3(16, 32), 256, 0, stream>>>(qbf, kbf, mc, cand, gcount);
  rescore<<<512, 256, 0, stream>>>(qf, kf, midx, cand, gcount, keys);
  assemble<<<16384, 256, 0, stream>>>(vf, sums, maskw, keys, out);
}

// Round 7
// 554.754 us; speedup vs baseline: 1.8145x; 1.8145x over previous
//
#include <hip/hip_runtime.h>
#include <hip/hip_bf16.h>
#include <cfloat>
#include <math.h>

typedef __bf16 bf16;
typedef __bf16 bf16x4 __attribute__((ext_vector_type(4)));
typedef __bf16 bf16x8 __attribute__((ext_vector_type(8)));
typedef float  floatx4 __attribute__((ext_vector_type(4)));
typedef float  floatx2 __attribute__((ext_vector_type(2)));

#define SEQ 2048
#define DM  1024
#define NP  2048
#define CAP (1 << 20)
#define MARGIN 0.5f

// ------- mask dtype detect + expand + order-preserving compaction + inits ----
__global__ __launch_bounds__(256) void mask_prep(
    const void* __restrict__ mraw, int* __restrict__ maskw,
    int* __restrict__ midx, int* __restrict__ mc,
    int* __restrict__ gcount, float* __restrict__ sums,
    unsigned long long* __restrict__ keys) {
  __shared__ int flags;
  __shared__ int lmask[2048];
  int t = threadIdx.x;
  if (t == 0) flags = 0;
  __syncthreads();
  const unsigned short* u16 = (const unsigned short*)mraw;
  const unsigned* u32 = (const unsigned*)mraw;
  int f = 0;
  for (int i = t; i < 1024; i += 256) {
    unsigned short v = u16[i];
    if (v != 0 && v != 0x3F80u) f |= 1;
    if ((i & 1) == 0 && v == 0x3F80u) f |= 2;
  }
  for (int i = t; i < 512; i += 256)
    if (u32[i] > 1u) f |= 4;
  if (f) atomicOr(&flags, f);
  if (t == 0) *gcount = 0;
  for (int i = t; i < 2048; i += 256) sums[i] = 0.f;
  for (int i = t; i < 16 * SEQ; i += 256) keys[i] = ~0ULL;
  __syncthreads();
  int fl = flags;
  int mode;
  if (!(fl & 1)) mode = (fl & 2) ? 2 : 3;
  else           mode = (fl & 4) ? 1 : 0;
  for (int s = t; s < SEQ; s += 256) {
    int m;
    if (mode == 0)      m = (((const int*)mraw)[s] != 0);
    else if (mode == 1) m = (((const unsigned char*)mraw)[s] != 0);
    else if (mode == 2) m = (u16[s] != 0);
    else                m = (((const float*)mraw)[s] != 0.0f);
    maskw[s] = m; lmask[s] = m;
  }
  __syncthreads();
  if (t < 64) {
    int base = 0;
    for (int c = 0; c < 32; c++) {
      int s = c * 64 + t;
      bool m = lmask[s] != 0;
      unsigned long long bal = __ballot(m);
      if (m) midx[base + __popcll(bal & ((1ULL << t) - 1ULL))] = s;
      base += __popcll(bal);
    }
    if (t == 0) *mc = base;
  }
}

// ------- W [1024][2048] -> transposed 3-way bf16 split WT_{h,m,l}[2048][1024] -
__global__ __launch_bounds__(256) void split_w(
    const float* __restrict__ W,
    bf16* __restrict__ Th, bf16* __restrict__ Tm, bf16* __restrict__ Tl) {
  __shared__ float tile[32][33];
  int n0 = blockIdx.x * 32, k0 = blockIdx.y * 32;
  int t = threadIdx.x, r = t >> 3, c4 = (t & 7) * 4;
  floatx4 v = *(const floatx4*)(W + (size_t)(k0 + r) * NP + n0 + c4);
  tile[r][c4 + 0] = v[0]; tile[r][c4 + 1] = v[1];
  tile[r][c4 + 2] = v[2]; tile[r][c4 + 3] = v[3];
  __syncthreads();
  bf16x4 hv, mv, lv;
  #pragma unroll
  for (int j = 0; j < 4; j++) {
    float x = tile[c4 + j][r];
    bf16 h = (bf16)x; float r1 = x - (float)h;
    bf16 m_ = (bf16)r1; float r2 = r1 - (float)m_;
    hv[j] = h; mv[j] = m_; lv[j] = (bf16)r2;
  }
  size_t base = (size_t)(n0 + r) * DM + k0 + c4;
  *(bf16x4*)(Th + base) = hv;
  *(bf16x4*)(Tm + base) = mv;
  *(bf16x4*)(Tl + base) = lv;
}

// ---- Q/K projection: 3-term split bf16 MFMA (6 products), fp32 accumulate ---
// A rows gathered from X via midx (compacted), split on the fly.
// Error vs true fp32 GEMM: repr ~2^-27, accumulation ~ fp32-chain — at/below
// numpy's own fp32 error, same flip-risk class as the fp64 versions (passed 4x).
__global__ __launch_bounds__(256) void proj_qk3(
    const float* __restrict__ X,
    const bf16* __restrict__ WTh, const bf16* __restrict__ WTm, const bf16* __restrict__ WTl,
    const float* __restrict__ bia,
    const int* __restrict__ midx, const int* __restrict__ mc,
    float* __restrict__ outf, bf16* __restrict__ outb) {
  int mcv = *mc;
  int ms = blockIdx.x * 128;
  if (mcv == 0 || ms >= mcv) return;
  int ns = blockIdx.y * 128, head = blockIdx.y;
  __shared__ alignas(16) bf16 Ah[128][40], Am[128][40], Al[128][40];
  __shared__ alignas(16) bf16 Bh[128][40], Bm[128][40], Bl[128][40];
  int t = threadIdx.x, w = t >> 6, lane = t & 63, l15 = lane & 15, qd = lane >> 4;
  int wm = (w >> 1) * 64, wn = (w & 1) * 64;
  int amr = t >> 1, akb = (t & 1) * 16;     // A staging: 128 rows x 32 k
  int bnr = t >> 1, bkb = (t & 1) * 16;     // B staging: 128 n x 32 k
  int cr = ms + amr;
  const float* xrow = X + (size_t)midx[cr < mcv ? cr : (mcv - 1)] * DM;
  const bf16* bhp = WTh + (size_t)(ns + bnr) * DM + bkb;
  const bf16* bmp = WTm + (size_t)(ns + bnr) * DM + bkb;
  const bf16* blp = WTl + (size_t)(ns + bnr) * DM + bkb;

  floatx4 acc[4][4];
  for (int i = 0; i < 4; i++)
    for (int j = 0; j < 4; j++) acc[i][j] = (floatx4){0.f, 0.f, 0.f, 0.f};

  for (int kt = 0; kt < DM; kt += 32) {
    floatx4 xa[4];
    #pragma unroll
    for (int u = 0; u < 4; u++)
      xa[u] = *(const floatx4*)(xrow + kt + akb + u * 4);
    bf16x8 wb[6];
    wb[0] = *(const bf16x8*)(bhp + kt);  wb[1] = *(const bf16x8*)(bhp + kt + 8);
    wb[2] = *(const bf16x8*)(bmp + kt);  wb[3] = *(const bf16x8*)(bmp + kt + 8);
    wb[4] = *(const bf16x8*)(blp + kt);  wb[5] = *(const bf16x8*)(blp + kt + 8);
    __syncthreads();
    bf16 ah8[16], am8[16], al8[16];
    #pragma unroll
    for (int u = 0; u < 4; u++)
      #pragma unroll
      for (int j = 0; j < 4; j++) {
        float v = xa[u][j];
        bf16 h = (bf16)v; float r1 = v - (float)h;
        bf16 m_ = (bf16)r1; float r2 = r1 - (float)m_;
        int e = u * 4 + j;
        ah8[e] = h; am8[e] = m_; al8[e] = (bf16)r2;
      }
    *(bf16x8*)&Ah[amr][akb]     = *(bf16x8*)&ah8[0];
    *(bf16x8*)&Ah[amr][akb + 8] = *(bf16x8*)&ah8[8];
    *(bf16x8*)&Am[amr][akb]     = *(bf16x8*)&am8[0];
    *(bf16x8*)&Am[amr][akb + 8] = *(bf16x8*)&am8[8];
    *(bf16x8*)&Al[amr][akb]     = *(bf16x8*)&al8[0];
    *(bf16x8*)&Al[amr][akb + 8] = *(bf16x8*)&al8[8];
    *(bf16x8*)&Bh[bnr][bkb]     = wb[0];
    *(bf16x8*)&Bh[bnr][bkb + 8] = wb[1];
    *(bf16x8*)&Bm[bnr][bkb]     = wb[2];
    *(bf16x8*)&Bm[bnr][bkb + 8] = wb[3];
    *(bf16x8*)&Bl[bnr][bkb]     = wb[4];
    *(bf16x8*)&Bl[bnr][bkb + 8] = wb[5];
    __syncthreads();
    bf16x8 fah[4], fam[4], fal[4], fbh[4], fbm[4], fbl[4];
    #pragma unroll
    for (int i = 0; i < 4; i++) {
      fah[i] = *(const bf16x8*)&Ah[wm + i * 16 + l15][qd * 8];
      fam[i] = *(const bf16x8*)&Am[wm + i * 16 + l15][qd * 8];
      fal[i] = *(const bf16x8*)&Al[wm + i * 16 + l15][qd * 8];
    }
    #pragma unroll
    for (int j = 0; j < 4; j++) {
      fbh[j] = *(const bf16x8*)&Bh[wn + j * 16 + l15][qd * 8];
      fbm[j] = *(const bf16x8*)&Bm[wn + j * 16 + l15][qd * 8];
      fbl[j] = *(const bf16x8*)&Bl[wn + j * 16 + l15][qd * 8];
    }
    #pragma unroll
    for (int i = 0; i < 4; i++)
      #pragma unroll
      for (int j = 0; j < 4; j++) {
        floatx4 a = acc[i][j];
        a = __builtin_amdgcn_mfma_f32_16x16x32_bf16(fal[i], fbh[j], a, 0, 0, 0);
        a = __builtin_amdgcn_mfma_f32_16x16x32_bf16(fah[i], fbl[j], a, 0, 0, 0);
        a = __builtin_amdgcn_mfma_f32_16x16x32_bf16(fam[i], fbm[j], a, 0, 0, 0);
        a = __builtin_amdgcn_mfma_f32_16x16x32_bf16(fam[i], fbh[j], a, 0, 0, 0);
        a = __builtin_amdgcn_mfma_f32_16x16x32_bf16(fah[i], fbm[j], a, 0, 0, 0);
        a = __builtin_amdgcn_mfma_f32_16x16x32_bf16(fah[i], fbh[j], a, 0, 0, 0);
        acc[i][j] = a;
      }
  }
  #pragma unroll
  for (int i = 0; i < 4; i++)
    #pragma unroll
    for (int j = 0; j < 4; j++) {
      int col = wn + j * 16 + l15;
      float bb = bia[ns + col];
      #pragma unroll
      for (int r = 0; r < 4; r++) {
        int row = ms + wm + i * 16 + qd * 4 + r;
        float v = acc[i][j][r] + bb;
        size_t idx = ((size_t)head * SEQ + row) * 128 + col;
        outf[idx] = v;
        outb[idx] = (bf16)v;
      }
    }
}

// -------- V projection via bf16 MFMA + fused column-sum (for the mean) ------
__global__ __launch_bounds__(256) void proj_v_mfma(
    const float* __restrict__ X, const float* __restrict__ W,
    const float* __restrict__ bia, float* __restrict__ out,
    float* __restrict__ sums) {
  __shared__ alignas(16) bf16 As[128][40];
  __shared__ alignas(16) bf16 Bs[128][40];
  __shared__ float colsum[128];
  int ms = blockIdx.x * 128, ns = blockIdx.y * 128;
  int t = threadIdx.x, w = t >> 6, lane = t & 63, l15 = lane & 15, qd = lane >> 4;
  int wm = (w >> 1) * 64, wn = (w & 1) * 64;
  int amr = t >> 1, akb = (t & 1) * 16;
  int bkr = t >> 3, bnb = (t & 7) * 16;
  if (t < 128) colsum[t] = 0.f;
  floatx4 acc[4][4];
  for (int i = 0; i < 4; i++)
    for (int j = 0; j < 4; j++) acc[i][j] = (floatx4){0.f, 0.f, 0.f, 0.f};

  for (int kt = 0; kt < DM; kt += 32) {
    floatx4 xa[4], wv[4];
    for (int u = 0; u < 4; u++)
      xa[u] = *(const floatx4*)(X + (size_t)(ms + amr) * DM + kt + akb + u * 4);
    for (int u = 0; u < 4; u++)
      wv[u] = *(const floatx4*)(W + (size_t)(kt + bkr) * NP + ns + bnb + u * 4);
    __syncthreads();
    {
      bf16x8 p0, p1;
      for (int j = 0; j < 4; j++) { p0[j] = (bf16)xa[0][j]; p0[4 + j] = (bf16)xa[1][j]; }
      for (int j = 0; j < 4; j++) { p1[j] = (bf16)xa[2][j]; p1[4 + j] = (bf16)xa[3][j]; }
      *(bf16x8*)&As[amr][akb]     = p0;
      *(bf16x8*)&As[amr][akb + 8] = p1;
    }
    for (int u = 0; u < 4; u++)
      for (int j = 0; j < 4; j++)
        Bs[bnb + u * 4 + j][bkr] = (bf16)wv[u][j];
    __syncthreads();
    bf16x8 af[4], bfr[4];
    for (int i = 0; i < 4; i++) af[i]  = *(const bf16x8*)&As[wm + i * 16 + l15][qd * 8];
    for (int j = 0; j < 4; j++) bfr[j] = *(const bf16x8*)&Bs[wn + j * 16 + l15][qd * 8];
    for (int i = 0; i < 4; i++)
      for (int j = 0; j < 4; j++)
        acc[i][j] = __builtin_amdgcn_mfma_f32_16x16x32_bf16(af[i], bfr[j], acc[i][j], 0, 0, 0);
  }
  float part[4] = {0.f, 0.f, 0.f, 0.f};
  for (int i = 0; i < 4; i++) {
    for (int j = 0; j < 4; j++) {
      int n = ns + wn + j * 16 + l15;
      float bb = bia[n];
      for (int r = 0; r < 4; r++) {
        int m = ms + wm + i * 16 + qd * 4 + r;
        float v = acc[i][j][r] + bb;
        out[(size_t)m * NP + n] = v;
        part[j] += v;
      }
    }
  }
  for (int j = 0; j < 4; j++)
    atomicAdd(&colsum[wn + j * 16 + l15], part[j]);
  __syncthreads();
  if (t < 128) atomicAdd(&sums[ns + t], colsum[t]);
}

// ------- approx scores on compacted rows (bf16 MFMA), candidate collect -----
__global__ __launch_bounds__(256) void scores_cand(
    const bf16* __restrict__ Qb, const bf16* __restrict__ Kb,
    const int* __restrict__ mc,
    unsigned* __restrict__ cand, int* __restrict__ gcount) {
  int mcv = *mc;
  int h = blockIdx.x, s0 = blockIdx.y * 64;
  if (s0 >= mcv) return;
  __shared__ float lmin[64][4];
  __shared__ float fmin[64];
  int t = threadIdx.x, w = t >> 6, lane = t & 63, l15 = lane & 15, qd = lane >> 4;
  const bf16* Qh = Qb + (size_t)h * SEQ * 128;
  const bf16* Kh = Kb + (size_t)h * SEQ * 128;

  bf16x8 af[4][4];
  for (int ksp = 0; ksp < 4; ksp++)
    for (int i = 0; i < 4; i++)
      af[ksp][i] = *(const bf16x8*)(Qh + (size_t)(s0 + i * 16 + l15) * 128 + ksp * 32 + qd * 8);

  int nt = (mcv + 63) >> 6;
  float rmin[4][4];
  for (int i = 0; i < 4; i++)
    for (int r = 0; r < 4; r++) rmin[i][r] = INFINITY;

  for (int tt = 0; tt < nt; tt++) {
    int t0 = tt * 64;
    floatx4 acc[4];
    for (int i = 0; i < 4; i++) acc[i] = (floatx4){0.f, 0.f, 0.f, 0.f};
    for (int ksp = 0; ksp < 4; ksp++) {
      bf16x8 bfr = *(const bf16x8*)(Kh + (size_t)(t0 + w * 16 + l15) * 128 + ksp * 32 + qd * 8);
      for (int i = 0; i < 4; i++)
        acc[i] = __builtin_amdgcn_mfma_f32_16x16x32_bf16(af[ksp][i], bfr, acc[i], 0, 0, 0);
    }
    bool okc = (t0 + w * 16 + l15) < mcv;
    for (int i = 0; i < 4; i++)
      for (int r = 0; r < 4; r++)
        rmin[i][r] = fminf(rmin[i][r], okc ? acc[i][r] : INFINITY);
  }
  for (int m = 1; m < 16; m <<= 1)
    for (int i = 0; i < 4; i++)
      for (int r = 0; r < 4; r++)
        rmin[i][r] = fminf(rmin[i][r], __shfl_xor(rmin[i][r], m));
  if (l15 == 0)
    for (int i = 0; i < 4; i++)
      for (int r = 0; r < 4; r++)
        lmin[i * 16 + qd * 4 + r][w] = rmin[i][r];
  __syncthreads();
  if (t < 64)
    fmin[t] = fminf(fminf(lmin[t][0], lmin[t][1]), fminf(lmin[t][2], lmin[t][3])) + MARGIN;
  __syncthreads();

  for (int tt = 0; tt < nt; tt++) {
    int t0 = tt * 64;
    floatx4 acc[4];
    for (int i = 0; i < 4; i++) acc[i] = (floatx4){0.f, 0.f, 0.f, 0.f};
    for (int ksp = 0; ksp < 4; ksp++) {
      bf16x8 bfr = *(const bf16x8*)(Kh + (size_t)(t0 + w * 16 + l15) * 128 + ksp * 32 + qd * 8);
      for (int i = 0; i < 4; i++)
        acc[i] = __builtin_amdgcn_mfma_f32_16x16x32_bf16(af[ksp][i], bfr, acc[i], 0, 0, 0);
    }
    int tg = t0 + w * 16 + l15;
    if (tg < mcv) {
      for (int i = 0; i < 4; i++)
        for (int r = 0; r < 4; r++) {
          int row = s0 + i * 16 + qd * 4 + r;
          if (row < mcv && acc[i][r] <= fmin[i * 16 + qd * 4 + r]) {
            int pos = atomicAdd(gcount, 1);
            if (pos < CAP)
              cand[pos] = ((unsigned)h << 22) | ((unsigned)row << 11) | (unsigned)tg;
          }
        }
    }
  }
}

// ---------------- fp64 exact rescore (compacted rows), atomicMin key --------
__global__ __launch_bounds__(256) void rescore(
    const float* __restrict__ Q, const float* __restrict__ K,
    const int* __restrict__ midx,
    const unsigned* __restrict__ cand, const int* __restrict__ gcount,
    unsigned long long* __restrict__ keys) {
  int wid  = (blockIdx.x * 256 + threadIdx.x) >> 6;
  int lane = threadIdx.x & 63;
  int nw = gridDim.x * 4;
  int n = *gcount; if (n > CAP) n = CAP;
  for (int c = wid; c < n; c += nw) {
    unsigned u = cand[c];
    int h = u >> 22, cs = (u >> 11) & 2047, ct = u & 2047;
    floatx2 qv = *(const floatx2*)(Q + ((size_t)h * SEQ + cs) * 128 + lane * 2);
    floatx2 kv = *(const floatx2*)(K + ((size_t)h * SEQ + ct) * 128 + lane * 2);
    double d = (double)qv[0] * (double)kv[0] + (double)qv[1] * (double)kv[1];
    for (int off = 32; off; off >>= 1) d += __shfl_down(d, off);
    if (lane == 0) {
      int sorig = midx[cs], torig = midx[ct];
      long long b = __double_as_longlong(d);
      unsigned long long ub = (b >= 0) ? ((unsigned long long)b | 0x8000000000000000ULL)
                                       : ~(unsigned long long)b;
      unsigned long long key = (ub & ~2047ULL) | (unsigned long long)torig;
      atomicMin(&keys[(size_t)h * SEQ + sorig], key);
    }
  }
}

// ---------------- gather / mean, fp32 out ----------------
__global__ __launch_bounds__(256) void assemble(
    const float* __restrict__ V, const float* __restrict__ sums,
    const int* __restrict__ mask, const unsigned long long* __restrict__ keys,
    float* __restrict__ out) {
  int idx = blockIdx.x * 256 + threadIdx.x;
  int s = idx >> 11, n = idx & 2047, h = n >> 7;
  float val;
  if (mask[s]) {
    int tt = (int)(keys[(size_t)h * SEQ + s] & 2047ULL);
    val = V[(size_t)tt * NP + n];
  } else {
    val = sums[n] * (1.0f / 2048.0f);
  }
  out[idx] = val;
}

extern "C" void kernel_launch(void* const* d_in, const int* in_sizes, int n_in,
                              void* d_out, int out_size, void* d_ws, size_t ws_size,
                              hipStream_t stream) {
  (void)in_sizes; (void)n_in; (void)out_size; (void)ws_size;
  const float* X    = (const float*)d_in[0];
  const void*  mraw = d_in[1];
  const float* Wq   = (const float*)d_in[2];
  const float* bq   = (const float*)d_in[3];
  const float* Wk   = (const float*)d_in[4];
  const float* bk   = (const float*)d_in[5];
  const float* Wv   = (const float*)d_in[6];
  const float* bv   = (const float*)d_in[7];

  char* ws = (char*)d_ws;
  float* qf  = (float*)ws;                                  // 0..16MB  [16][2048][128] fp32
  float* kf  = (float*)(ws + ((size_t)16 << 20));           // 16..32MB
  bf16*  qbf = (bf16*) (ws + ((size_t)32 << 20));           // 32..40MB bf16 copies
  bf16*  kbf = (bf16*) (ws + ((size_t)40 << 20));           // 40..48MB
  // region B (48..68MB): W splits (12MB, dead after proj_qk3) overlaid by vf+cand
  bf16*  wth = (bf16*) (ws + ((size_t)48 << 20));           // 4MB [2048][1024]
  bf16*  wtm = (bf16*) (ws + ((size_t)52 << 20));           // 4MB
  bf16*  wtl = (bf16*) (ws + ((size_t)56 << 20));           // 4MB
  float* vf  = (float*)(ws + ((size_t)48 << 20));           // 16MB (after proj_qk3)
  unsigned* cand = (unsigned*)(ws + ((size_t)64 << 20));    // 4MB
  char* misc = ws + ((size_t)68 << 20);
  int*   maskw  = (int*)misc;                               // 8KB
  int*   midx   = (int*)(misc + (8 << 10));                 // 8KB
  int*   mc     = (int*)(misc + (16 << 10));                // 4B
  int*   gcount = (int*)(misc + (16 << 10) + 64);           // 4B
  float* sums   = (float*)(misc + (32 << 10));              // 8KB
  unsigned long long* keys = (unsigned long long*)(misc + (64 << 10)); // 256KB
  float* out = (float*)d_out;

  mask_prep<<<1, 256, 0, stream>>>(mraw, maskw, midx, mc, gcount, sums, keys);
  split_w<<<dim3(64, 32), 256, 0, stream>>>(Wq, wth, wtm, wtl);
  proj_qk3<<<dim3(16, 16), 256, 0, stream>>>(X, wth, wtm, wtl, bq, midx, mc, qf, qbf);
  split_w<<<dim3(64, 32), 256, 0, stream>>>(Wk, wth, wtm, wtl);
  proj_qk3<<<dim3(16, 16), 256, 0, stream>>>(X, wth, wtm, wtl, bk, midx, mc, kf, kbf);
  proj_v_mfma<<<dim3(16, 16), 256, 0, stream>>>(X, Wv, bv, vf, sums);
  scores_cand<<<dim3(16, 32), 256, 0, stream>>>(qbf, kbf, mc, cand, gcount);
  rescore<<<512, 256, 0, stream>>>(qf, kf, midx, cand, gcount, keys);
  assemble<<<16384, 256, 0, stream>>>(vf, sums, maskw, keys, out);
}

// Round 9
// 533.325 us; speedup vs baseline: 1.8874x; 1.0402x over previous
//
#include <hip/hip_runtime.h>
#include <hip/hip_bf16.h>
#include <cfloat>
#include <math.h>

typedef __bf16 bf16;
typedef __bf16 bf16x4 __attribute__((ext_vector_type(4)));
typedef __bf16 bf16x8 __attribute__((ext_vector_type(8)));
typedef float  floatx4 __attribute__((ext_vector_type(4)));
typedef float  floatx2 __attribute__((ext_vector_type(2)));

#define SEQ 2048
#define DM  1024
#define NP  2048
#define CAP (1 << 20)
#define MARGIN 0.5f

__device__ __forceinline__ unsigned enc_f(float f) {
  unsigned b = __float_as_uint(f);
  return ((int)b >= 0) ? (b | 0x80000000u) : ~b;
}
__device__ __forceinline__ float dec_f(unsigned u) {
  return (u & 0x80000000u) ? __uint_as_float(u & 0x7fffffffu) : __uint_as_float(~u);
}

// ------- mask detect + compaction (block 0) + parallel inits (blocks 1..32) --
__global__ __launch_bounds__(256) void mask_prep(
    const void* __restrict__ mraw, int* __restrict__ maskw,
    int* __restrict__ midx, int* __restrict__ mc,
    int* __restrict__ gcount, int* __restrict__ pcount,
    float* __restrict__ sums, unsigned long long* __restrict__ keys,
    unsigned* __restrict__ gmin) {
  int t = threadIdx.x;
  if (blockIdx.x > 0) {
    int b = blockIdx.x - 1;                 // 0..31
    for (int j = 0; j < 4; j++) {
      int i = b * 1024 + j * 256 + t;
      keys[i] = ~0ULL;
      gmin[i] = 0xFFFFFFFFu;
    }
    if (b == 0) for (int i = t; i < 2048; i += 256) sums[i] = 0.f;
    return;
  }
  __shared__ int flags;
  __shared__ int lmask[2048];
  if (t == 0) { flags = 0; *gcount = 0; *pcount = 0; }
  __syncthreads();
  const unsigned short* u16 = (const unsigned short*)mraw;
  const unsigned* u32 = (const unsigned*)mraw;
  int f = 0;
  for (int i = t; i < 1024; i += 256) {
    unsigned short v = u16[i];
    if (v != 0 && v != 0x3F80u) f |= 1;
    if ((i & 1) == 0 && v == 0x3F80u) f |= 2;
  }
  for (int i = t; i < 512; i += 256)
    if (u32[i] > 1u) f |= 4;
  if (f) atomicOr(&flags, f);
  __syncthreads();
  int fl = flags;
  int mode;
  if (!(fl & 1)) mode = (fl & 2) ? 2 : 3;
  else           mode = (fl & 4) ? 1 : 0;
  for (int s = t; s < SEQ; s += 256) {
    int m;
    if (mode == 0)      m = (((const int*)mraw)[s] != 0);
    else if (mode == 1) m = (((const unsigned char*)mraw)[s] != 0);
    else if (mode == 2) m = (u16[s] != 0);
    else                m = (((const float*)mraw)[s] != 0.0f);
    maskw[s] = m; lmask[s] = m;
  }
  __syncthreads();
  if (t < 64) {
    int base = 0;
    for (int c = 0; c < 32; c++) {
      int s = c * 64 + t;
      bool m = lmask[s] != 0;
      unsigned long long bal = __ballot(m);
      if (m) midx[base + __popcll(bal & ((1ULL << t) - 1ULL))] = s;
      base += __popcll(bal);
    }
    if (t == 0) *mc = base;
  }
}

// ------- W [1024][2048] -> transposed 3-way bf16 split (Q and K via z) -------
__global__ __launch_bounds__(256) void split_w(
    const float* __restrict__ Wq, const float* __restrict__ Wk,
    bf16* __restrict__ Tqh, bf16* __restrict__ Tqm, bf16* __restrict__ Tql,
    bf16* __restrict__ Tkh, bf16* __restrict__ Tkm, bf16* __restrict__ Tkl) {
  const float* W = blockIdx.z ? Wk : Wq;
  bf16* Th = blockIdx.z ? Tkh : Tqh;
  bf16* Tm = blockIdx.z ? Tkm : Tqm;
  bf16* Tl = blockIdx.z ? Tkl : Tql;
  __shared__ float tile[32][33];
  int n0 = blockIdx.x * 32, k0 = blockIdx.y * 32;
  int t = threadIdx.x, r = t >> 3, c4 = (t & 7) * 4;
  floatx4 v = *(const floatx4*)(W + (size_t)(k0 + r) * NP + n0 + c4);
  tile[r][c4 + 0] = v[0]; tile[r][c4 + 1] = v[1];
  tile[r][c4 + 2] = v[2]; tile[r][c4 + 3] = v[3];
  __syncthreads();
  bf16x4 hv, mv, lv;
  #pragma unroll
  for (int j = 0; j < 4; j++) {
    float x = tile[c4 + j][r];
    bf16 h = (bf16)x; float r1 = x - (float)h;
    bf16 m_ = (bf16)r1; float r2 = r1 - (float)m_;
    hv[j] = h; mv[j] = m_; lv[j] = (bf16)r2;
  }
  size_t base = (size_t)(n0 + r) * DM + k0 + c4;
  *(bf16x4*)(Th + base) = hv;
  *(bf16x4*)(Tm + base) = mv;
  *(bf16x4*)(Tl + base) = lv;
}

// ---- Q/K projection: 3-term split bf16 MFMA (6 products), fp32 acc; z=Q/K ---
__global__ __launch_bounds__(256) void proj_qk3(
    const float* __restrict__ X,
    const bf16* __restrict__ Qh_, const bf16* __restrict__ Qm_, const bf16* __restrict__ Ql_,
    const bf16* __restrict__ Kh_, const bf16* __restrict__ Km_, const bf16* __restrict__ Kl_,
    const float* __restrict__ bq, const float* __restrict__ bk,
    const int* __restrict__ midx, const int* __restrict__ mc,
    float* __restrict__ qf, float* __restrict__ kf,
    bf16* __restrict__ qbf, bf16* __restrict__ kbf) {
  int mcv = *mc;
  int ms = blockIdx.x * 128;
  if (mcv == 0 || ms >= mcv) return;
  int z = blockIdx.z;
  const bf16* WTh = z ? Kh_ : Qh_;
  const bf16* WTm = z ? Km_ : Qm_;
  const bf16* WTl = z ? Kl_ : Ql_;
  const float* bia = z ? bk : bq;
  float* outf = z ? kf : qf;
  bf16*  outb = z ? kbf : qbf;
  int ns = blockIdx.y * 128, head = blockIdx.y;
  __shared__ alignas(16) bf16 Ah[128][40], Am[128][40], Al[128][40];
  __shared__ alignas(16) bf16 Bh[128][40], Bm[128][40], Bl[128][40];
  int t = threadIdx.x, w = t >> 6, lane = t & 63, l15 = lane & 15, qd = lane >> 4;
  int wm = (w >> 1) * 64, wn = (w & 1) * 64;
  int amr = t >> 1, akb = (t & 1) * 16;
  int bnr = t >> 1, bkb = (t & 1) * 16;
  int cr = ms + amr;
  const float* xrow = X + (size_t)midx[cr < mcv ? cr : (mcv - 1)] * DM;
  const bf16* bhp = WTh + (size_t)(ns + bnr) * DM + bkb;
  const bf16* bmp = WTm + (size_t)(ns + bnr) * DM + bkb;
  const bf16* blp = WTl + (size_t)(ns + bnr) * DM + bkb;

  floatx4 acc[4][4];
  for (int i = 0; i < 4; i++)
    for (int j = 0; j < 4; j++) acc[i][j] = (floatx4){0.f, 0.f, 0.f, 0.f};

  for (int kt = 0; kt < DM; kt += 32) {
    floatx4 xa[4];
    #pragma unroll
    for (int u = 0; u < 4; u++)
      xa[u] = *(const floatx4*)(xrow + kt + akb + u * 4);
    bf16x8 wb[6];
    wb[0] = *(const bf16x8*)(bhp + kt);  wb[1] = *(const bf16x8*)(bhp + kt + 8);
    wb[2] = *(const bf16x8*)(bmp + kt);  wb[3] = *(const bf16x8*)(bmp + kt + 8);
    wb[4] = *(const bf16x8*)(blp + kt);  wb[5] = *(const bf16x8*)(blp + kt + 8);
    __syncthreads();
    bf16 ah8[16], am8[16], al8[16];
    #pragma unroll
    for (int u = 0; u < 4; u++)
      #pragma unroll
      for (int j = 0; j < 4; j++) {
        float v = xa[u][j];
        bf16 h = (bf16)v; float r1 = v - (float)h;
        bf16 m_ = (bf16)r1; float r2 = r1 - (float)m_;
        int e = u * 4 + j;
        ah8[e] = h; am8[e] = m_; al8[e] = (bf16)r2;
      }
    *(bf16x8*)&Ah[amr][akb]     = *(bf16x8*)&ah8[0];
    *(bf16x8*)&Ah[amr][akb + 8] = *(bf16x8*)&ah8[8];
    *(bf16x8*)&Am[amr][akb]     = *(bf16x8*)&am8[0];
    *(bf16x8*)&Am[amr][akb + 8] = *(bf16x8*)&am8[8];
    *(bf16x8*)&Al[amr][akb]     = *(bf16x8*)&al8[0];
    *(bf16x8*)&Al[amr][akb + 8] = *(bf16x8*)&al8[8];
    *(bf16x8*)&Bh[bnr][bkb]     = wb[0];
    *(bf16x8*)&Bh[bnr][bkb + 8] = wb[1];
    *(bf16x8*)&Bm[bnr][bkb]     = wb[2];
    *(bf16x8*)&Bm[bnr][bkb + 8] = wb[3];
    *(bf16x8*)&Bl[bnr][bkb]     = wb[4];
    *(bf16x8*)&Bl[bnr][bkb + 8] = wb[5];
    __syncthreads();
    bf16x8 fah[4], fam[4], fal[4], fbh[4], fbm[4], fbl[4];
    #pragma unroll
    for (int i = 0; i < 4; i++) {
      fah[i] = *(const bf16x8*)&Ah[wm + i * 16 + l15][qd * 8];
      fam[i] = *(const bf16x8*)&Am[wm + i * 16 + l15][qd * 8];
      fal[i] = *(const bf16x8*)&Al[wm + i * 16 + l15][qd * 8];
    }
    #pragma unroll
    for (int j = 0; j < 4; j++) {
      fbh[j] = *(const bf16x8*)&Bh[wn + j * 16 + l15][qd * 8];
      fbm[j] = *(const bf16x8*)&Bm[wn + j * 16 + l15][qd * 8];
      fbl[j] = *(const bf16x8*)&Bl[wn + j * 16 + l15][qd * 8];
    }
    #pragma unroll
    for (int i = 0; i < 4; i++)
      #pragma unroll
      for (int j = 0; j < 4; j++) {
        floatx4 a = acc[i][j];
        a = __builtin_amdgcn_mfma_f32_16x16x32_bf16(fal[i], fbh[j], a, 0, 0, 0);
        a = __builtin_amdgcn_mfma_f32_16x16x32_bf16(fah[i], fbl[j], a, 0, 0, 0);
        a = __builtin_amdgcn_mfma_f32_16x16x32_bf16(fam[i], fbm[j], a, 0, 0, 0);
        a = __builtin_amdgcn_mfma_f32_16x16x32_bf16(fam[i], fbh[j], a, 0, 0, 0);
        a = __builtin_amdgcn_mfma_f32_16x16x32_bf16(fah[i], fbm[j], a, 0, 0, 0);
        a = __builtin_amdgcn_mfma_f32_16x16x32_bf16(fah[i], fbh[j], a, 0, 0, 0);
        acc[i][j] = a;
      }
  }
  #pragma unroll
  for (int i = 0; i < 4; i++)
    #pragma unroll
    for (int j = 0; j < 4; j++) {
      int col = wn + j * 16 + l15;
      float bb = bia[ns + col];
      #pragma unroll
      for (int r = 0; r < 4; r++) {
        int row = ms + wm + i * 16 + qd * 4 + r;
        float v = acc[i][j][r] + bb;
        size_t idx = ((size_t)head * SEQ + row) * 128 + col;
        outf[idx] = v;
        outb[idx] = (bf16)v;
      }
    }
}

// -------- V projection via bf16 MFMA + fused column-sum (for the mean) ------
__global__ __launch_bounds__(256) void proj_v_mfma(
    const float* __restrict__ X, const float* __restrict__ W,
    const float* __restrict__ bia, float* __restrict__ out,
    float* __restrict__ sums) {
  __shared__ alignas(16) bf16 As[128][40];
  __shared__ alignas(16) bf16 Bs[128][40];
  __shared__ float colsum[128];
  int ms = blockIdx.x * 128, ns = blockIdx.y * 128;
  int t = threadIdx.x, w = t >> 6, lane = t & 63, l15 = lane & 15, qd = lane >> 4;
  int wm = (w >> 1) * 64, wn = (w & 1) * 64;
  int amr = t >> 1, akb = (t & 1) * 16;
  int bkr = t >> 3, bnb = (t & 7) * 16;
  if (t < 128) colsum[t] = 0.f;
  floatx4 acc[4][4];
  for (int i = 0; i < 4; i++)
    for (int j = 0; j < 4; j++) acc[i][j] = (floatx4){0.f, 0.f, 0.f, 0.f};

  for (int kt = 0; kt < DM; kt += 32) {
    floatx4 xa[4], wv[4];
    for (int u = 0; u < 4; u++)
      xa[u] = *(const floatx4*)(X + (size_t)(ms + amr) * DM + kt + akb + u * 4);
    for (int u = 0; u < 4; u++)
      wv[u] = *(const floatx4*)(W + (size_t)(kt + bkr) * NP + ns + bnb + u * 4);
    __syncthreads();
    {
      bf16x8 p0, p1;
      for (int j = 0; j < 4; j++) { p0[j] = (bf16)xa[0][j]; p0[4 + j] = (bf16)xa[1][j]; }
      for (int j = 0; j < 4; j++) { p1[j] = (bf16)xa[2][j]; p1[4 + j] = (bf16)xa[3][j]; }
      *(bf16x8*)&As[amr][akb]     = p0;
      *(bf16x8*)&As[amr][akb + 8] = p1;
    }
    for (int u = 0; u < 4; u++)
      for (int j = 0; j < 4; j++)
        Bs[bnb + u * 4 + j][bkr] = (bf16)wv[u][j];
    __syncthreads();
    bf16x8 af[4], bfr[4];
    for (int i = 0; i < 4; i++) af[i]  = *(const bf16x8*)&As[wm + i * 16 + l15][qd * 8];
    for (int j = 0; j < 4; j++) bfr[j] = *(const bf16x8*)&Bs[wn + j * 16 + l15][qd * 8];
    for (int i = 0; i < 4; i++)
      for (int j = 0; j < 4; j++)
        acc[i][j] = __builtin_amdgcn_mfma_f32_16x16x32_bf16(af[i], bfr[j], acc[i][j], 0, 0, 0);
  }
  float part[4] = {0.f, 0.f, 0.f, 0.f};
  for (int i = 0; i < 4; i++) {
    for (int j = 0; j < 4; j++) {
      int n = ns + wn + j * 16 + l15;
      float bb = bia[n];
      for (int r = 0; r < 4; r++) {
        int m = ms + wm + i * 16 + qd * 4 + r;
        float v = acc[i][j][r] + bb;
        out[(size_t)m * NP + n] = v;
        part[j] += v;
      }
    }
  }
  for (int j = 0; j < 4; j++)
    atomicAdd(&colsum[wn + j * 16 + l15], part[j]);
  __syncthreads();
  if (t < 128) atomicAdd(&sums[ns + t], colsum[t]);
}

// ------- S1: approx scores (bf16 MFMA), per-(row,chunk) min + global min ----
__global__ __launch_bounds__(256) void scores_min(
    const bf16* __restrict__ Qb, const bf16* __restrict__ Kb,
    const int* __restrict__ mc,
    float* __restrict__ tmin, unsigned* __restrict__ gmin) {
  int mcv = *mc;
  int h = blockIdx.x, s0 = blockIdx.y * 64, chunk = blockIdx.z;
  if (s0 >= mcv) return;
  int ntiles = (mcv + 63) >> 6;
  __shared__ float lmin[64][4];
  int t = threadIdx.x, w = t >> 6, lane = t & 63, l15 = lane & 15, qd = lane >> 4;
  const bf16* Qh = Qb + (size_t)h * SEQ * 128;
  const bf16* Kh = Kb + (size_t)h * SEQ * 128;
  bf16x8 af[4][4];
  for (int ksp = 0; ksp < 4; ksp++)
    for (int i = 0; i < 4; i++)
      af[ksp][i] = *(const bf16x8*)(Qh + (size_t)(s0 + i * 16 + l15) * 128 + ksp * 32 + qd * 8);
  float rmin[4][4];
  for (int i = 0; i < 4; i++)
    for (int r = 0; r < 4; r++) rmin[i][r] = INFINITY;

  for (int tt = chunk; tt < ntiles; tt += 8) {
    int t0 = tt * 64;
    floatx4 acc[4];
    for (int i = 0; i < 4; i++) acc[i] = (floatx4){0.f, 0.f, 0.f, 0.f};
    for (int ksp = 0; ksp < 4; ksp++) {
      bf16x8 bfr = *(const bf16x8*)(Kh + (size_t)(t0 + w * 16 + l15) * 128 + ksp * 32 + qd * 8);
      for (int i = 0; i < 4; i++)
        acc[i] = __builtin_amdgcn_mfma_f32_16x16x32_bf16(af[ksp][i], bfr, acc[i], 0, 0, 0);
    }
    bool okc = (t0 + w * 16 + l15) < mcv;
    for (int i = 0; i < 4; i++)
      for (int r = 0; r < 4; r++)
        rmin[i][r] = fminf(rmin[i][r], okc ? acc[i][r] : INFINITY);
  }
  for (int m = 1; m < 16; m <<= 1)
    for (int i = 0; i < 4; i++)
      for (int r = 0; r < 4; r++)
        rmin[i][r] = fminf(rmin[i][r], __shfl_xor(rmin[i][r], m));
  if (l15 == 0)
    for (int i = 0; i < 4; i++)
      for (int r = 0; r < 4; r++)
        lmin[i * 16 + qd * 4 + r][w] = rmin[i][r];
  __syncthreads();
  if (t < 64) {
    int row = s0 + t;
    if (row < mcv) {
      float cm = fminf(fminf(lmin[t][0], lmin[t][1]), fminf(lmin[t][2], lmin[t][3]));
      tmin[((size_t)h * 2048 + row) * 8 + chunk] = cm;
      atomicMin(&gmin[h * 2048 + row], enc_f(cm));
    }
  }
}

// ------- S2: enumerate qualifying (h,row,chunk) pairs ----------------------
__global__ __launch_bounds__(256) void cand_enum(
    const float* __restrict__ tmin, const unsigned* __restrict__ gmin,
    const int* __restrict__ mc,
    unsigned* __restrict__ pairs, int* __restrict__ pcount) {
  int mcv = *mc;
  int idx = blockIdx.x * 256 + threadIdx.x;
  for (int i = idx; i < 16 * 2048 * 8; i += 65536) {
    int row = (i >> 3) & 2047;
    if (row >= mcv) continue;
    int h = i >> 14;
    float fm = dec_f(gmin[h * 2048 + row]) + MARGIN;
    if (tmin[i] <= fm) {
      int p = atomicAdd(pcount, 1);
      pairs[p] = (unsigned)i;
    }
  }
}

// ------- S3: fp32 dots over flagged chunks -> candidates -------------------
// Each thread handles row tl=t>>2, dims d0..d0+31 — loads its K segment
// DIRECTLY from global into registers (no LDS staging; r8's staging bug fix).
__global__ __launch_bounds__(256) void cand_dots(
    const bf16* __restrict__ Qb, const bf16* __restrict__ Kb,
    const int* __restrict__ mc,
    const unsigned* __restrict__ pairs, const int* __restrict__ pcount,
    const unsigned* __restrict__ gmin,
    unsigned* __restrict__ cand, int* __restrict__ gcount) {
  int mcv = *mc;
  int np = *pcount;
  int ntiles = (mcv + 63) >> 6;
  __shared__ float qs[128];
  int t = threadIdx.x;
  int tl = t >> 2, d0 = (t & 3) * 32;
  for (int p = blockIdx.x; p < np; p += gridDim.x) {
    unsigned pk = pairs[p];
    int h = pk >> 14, row = (pk >> 3) & 2047, c = pk & 7;
    const bf16* Qr = Qb + ((size_t)h * SEQ + row) * 128;
    const bf16* Kh = Kb + (size_t)h * SEQ * 128;
    __syncthreads();                         // prior iteration's qs reads done
    if (t < 128) qs[t] = (float)Qr[t];
    __syncthreads();
    float fm = dec_f(gmin[h * 2048 + row]) + MARGIN;
    for (int tt = c; tt < ntiles; tt += 8) {
      int tg = tt * 64 + tl;
      const bf16* kr = Kh + (size_t)tg * 128 + d0;
      bf16x8 k0 = *(const bf16x8*)(kr);
      bf16x8 k1 = *(const bf16x8*)(kr + 8);
      bf16x8 k2 = *(const bf16x8*)(kr + 16);
      bf16x8 k3 = *(const bf16x8*)(kr + 24);
      float s = 0.f;
      #pragma unroll
      for (int d = 0; d < 8; d++) {
        s += qs[d0 + d]      * (float)k0[d];
        s += qs[d0 + 8 + d]  * (float)k1[d];
        s += qs[d0 + 16 + d] * (float)k2[d];
        s += qs[d0 + 24 + d] * (float)k3[d];
      }
      s += __shfl_xor(s, 1);
      s += __shfl_xor(s, 2);
      if ((t & 3) == 0 && tg < mcv && s <= fm) {
        int pos = atomicAdd(gcount, 1);
        if (pos < CAP)
          cand[pos] = ((unsigned)h << 22) | ((unsigned)row << 11) | (unsigned)tg;
      }
    }
  }
}

// ---------------- fp64 exact rescore (compacted rows), atomicMin key --------
__global__ __launch_bounds__(256) void rescore(
    const float* __restrict__ Q, const float* __restrict__ K,
    const int* __restrict__ midx,
    const unsigned* __restrict__ cand, const int* __restrict__ gcount,
    unsigned long long* __restrict__ keys) {
  int wid  = (blockIdx.x * 256 + threadIdx.x) >> 6;
  int lane = threadIdx.x & 63;
  int nw = gridDim.x * 4;
  int n = *gcount; if (n > CAP) n = CAP;
  for (int c = wid; c < n; c += nw) {
    unsigned u = cand[c];
    int h = u >> 22, cs = (u >> 11) & 2047, ct = u & 2047;
    floatx2 qv = *(const floatx2*)(Q + ((size_t)h * SEQ + cs) * 128 + lane * 2);
    floatx2 kv = *(const floatx2*)(K + ((size_t)h * SEQ + ct) * 128 + lane * 2);
    double d = (double)qv[0] * (double)kv[0] + (double)qv[1] * (double)kv[1];
    for (int off = 32; off; off >>= 1) d += __shfl_down(d, off);
    if (lane == 0) {
      int sorig = midx[cs], torig = midx[ct];
      long long b = __double_as_longlong(d);
      unsigned long long ub = (b >= 0) ? ((unsigned long long)b | 0x8000000000000000ULL)
                                       : ~(unsigned long long)b;
      unsigned long long key = (ub & ~2047ULL) | (unsigned long long)torig;
      atomicMin(&keys[(size_t)h * SEQ + sorig], key);
    }
  }
}

// ---------------- gather / mean, fp32 out ----------------
__global__ __launch_bounds__(256) void assemble(
    const float* __restrict__ V, const float* __restrict__ sums,
    const int* __restrict__ mask, const unsigned long long* __restrict__ keys,
    float* __restrict__ out) {
  int idx = blockIdx.x * 256 + threadIdx.x;
  int s = idx >> 11, n = idx & 2047, h = n >> 7;
  float val;
  if (mask[s]) {
    int tt = (int)(keys[(size_t)h * SEQ + s] & 2047ULL);
    val = V[(size_t)tt * NP + n];
  } else {
    val = sums[n] * (1.0f / 2048.0f);
  }
  out[idx] = val;
}

extern "C" void kernel_launch(void* const* d_in, const int* in_sizes, int n_in,
                              void* d_out, int out_size, void* d_ws, size_t ws_size,
                              hipStream_t stream) {
  (void)in_sizes; (void)n_in; (void)out_size; (void)ws_size;
  const float* X    = (const float*)d_in[0];
  const void*  mraw = d_in[1];
  const float* Wq   = (const float*)d_in[2];
  const float* bq   = (const float*)d_in[3];
  const float* Wk   = (const float*)d_in[4];
  const float* bk   = (const float*)d_in[5];
  const float* Wv   = (const float*)d_in[6];
  const float* bv   = (const float*)d_in[7];

  char* ws = (char*)d_ws;
  float* qf  = (float*)ws;                                  // 0..16MB
  float* kf  = (float*)(ws + ((size_t)16 << 20));           // 16..32MB
  bf16*  qbf = (bf16*) (ws + ((size_t)32 << 20));           // 32..40MB
  bf16*  kbf = (bf16*) (ws + ((size_t)40 << 20));           // 40..48MB
  // 48..72MB: W splits (dead after proj_qk3), then overlaid by vf + cand
  bf16* wqh = (bf16*)(ws + ((size_t)48 << 20));
  bf16* wqm = (bf16*)(ws + ((size_t)52 << 20));
  bf16* wql = (bf16*)(ws + ((size_t)56 << 20));
  bf16* wkh = (bf16*)(ws + ((size_t)60 << 20));
  bf16* wkm = (bf16*)(ws + ((size_t)64 << 20));
  bf16* wkl = (bf16*)(ws + ((size_t)68 << 20));
  float* vf = (float*)(ws + ((size_t)48 << 20));            // 16MB (after proj_qk3)
  unsigned* cand = (unsigned*)(ws + ((size_t)64 << 20));    // 4MB  (after proj_qk3)
  char* misc = ws + ((size_t)72 << 20);
  int*   maskw  = (int*)misc;                                   // 8KB
  int*   midx   = (int*)(misc + (8 << 10));                     // 8KB
  int*   mc     = (int*)(misc + (16 << 10));                    // 4B
  int*   gcount = (int*)(misc + (16 << 10) + 64);               // 4B
  int*   pcount = (int*)(misc + (16 << 10) + 128);              // 4B
  float* sums   = (float*)(misc + (32 << 10));                  // 8KB
  unsigned long long* keys = (unsigned long long*)(misc + (64 << 10));  // 256KB
  unsigned* gmin = (unsigned*)(misc + (320 << 10));             // 128KB
  float*    tmin = (float*)(misc + (448 << 10));                // 1MB
  unsigned* pairs = (unsigned*)(misc + (1472 << 10));           // 1MB
  float* out = (float*)d_out;

  mask_prep<<<33, 256, 0, stream>>>(mraw, maskw, midx, mc, gcount, pcount, sums, keys, gmin);
  split_w<<<dim3(64, 32, 2), 256, 0, stream>>>(Wq, Wk, wqh, wqm, wql, wkh, wkm, wkl);
  proj_qk3<<<dim3(16, 16, 2), 256, 0, stream>>>(X, wqh, wqm, wql, wkh, wkm, wkl,
                                                bq, bk, midx, mc, qf, kf, qbf, kbf);
  proj_v_mfma<<<dim3(16, 16), 256, 0, stream>>>(X, Wv, bv, vf, sums);
  scores_min<<<dim3(16, 32, 8), 256, 0, stream>>>(qbf, kbf, mc, tmin, gmin);
  cand_enum<<<256, 256, 0, stream>>>(tmin, gmin, mc, pairs, pcount);
  cand_dots<<<2048, 256, 0, stream>>>(qbf, kbf, mc, pairs, pcount, gmin, cand, gcount);
  rescore<<<512, 256, 0, stream>>>(qf, kf, midx, cand, gcount, keys);
  assemble<<<16384, 256, 0, stream>>>(vf, sums, maskw, keys, out);
}

// Round 10
// 507.736 us; speedup vs baseline: 1.9826x; 1.0504x over previous
//
#include <hip/hip_runtime.h>
#include <hip/hip_bf16.h>
#include <cfloat>
#include <math.h>

typedef __bf16 bf16;
typedef __bf16 bf16x4 __attribute__((ext_vector_type(4)));
typedef __bf16 bf16x8 __attribute__((ext_vector_type(8)));
typedef float  floatx4 __attribute__((ext_vector_type(4)));
typedef float  floatx2 __attribute__((ext_vector_type(2)));

#define SEQ 2048
#define DM  1024
#define NP  2048
#define CAP (1 << 20)
#define MARGIN 0.5f

__device__ __forceinline__ unsigned enc_f(float f) {
  unsigned b = __float_as_uint(f);
  return ((int)b >= 0) ? (b | 0x80000000u) : ~b;
}
__device__ __forceinline__ float dec_f(unsigned u) {
  return (u & 0x80000000u) ? __uint_as_float(u & 0x7fffffffu) : __uint_as_float(~u);
}

// ------- mask detect + compaction (block 0) + parallel inits (blocks 1..32) --
__global__ __launch_bounds__(256) void mask_prep(
    const void* __restrict__ mraw, int* __restrict__ maskw,
    int* __restrict__ midx, int* __restrict__ mc,
    int* __restrict__ gcount, int* __restrict__ pcount,
    float* __restrict__ sums, unsigned long long* __restrict__ keys,
    unsigned* __restrict__ gmin) {
  int t = threadIdx.x;
  if (blockIdx.x > 0) {
    int b = blockIdx.x - 1;                 // 0..31
    for (int j = 0; j < 4; j++) {
      int i = b * 1024 + j * 256 + t;
      keys[i] = ~0ULL;
      gmin[i] = 0xFFFFFFFFu;
    }
    if (b == 0) for (int i = t; i < 2048; i += 256) sums[i] = 0.f;
    return;
  }
  __shared__ int flags;
  __shared__ int lmask[2048];
  if (t == 0) { flags = 0; *gcount = 0; *pcount = 0; }
  __syncthreads();
  const unsigned short* u16 = (const unsigned short*)mraw;
  const unsigned* u32 = (const unsigned*)mraw;
  int f = 0;
  for (int i = t; i < 1024; i += 256) {
    unsigned short v = u16[i];
    if (v != 0 && v != 0x3F80u) f |= 1;
    if ((i & 1) == 0 && v == 0x3F80u) f |= 2;
  }
  for (int i = t; i < 512; i += 256)
    if (u32[i] > 1u) f |= 4;
  if (f) atomicOr(&flags, f);
  __syncthreads();
  int fl = flags;
  int mode;
  if (!(fl & 1)) mode = (fl & 2) ? 2 : 3;
  else           mode = (fl & 4) ? 1 : 0;
  for (int s = t; s < SEQ; s += 256) {
    int m;
    if (mode == 0)      m = (((const int*)mraw)[s] != 0);
    else if (mode == 1) m = (((const unsigned char*)mraw)[s] != 0);
    else if (mode == 2) m = (u16[s] != 0);
    else                m = (((const float*)mraw)[s] != 0.0f);
    maskw[s] = m; lmask[s] = m;
  }
  __syncthreads();
  if (t < 64) {
    int base = 0;
    for (int c = 0; c < 32; c++) {
      int s = c * 64 + t;
      bool m = lmask[s] != 0;
      unsigned long long bal = __ballot(m);
      if (m) midx[base + __popcll(bal & ((1ULL << t) - 1ULL))] = s;
      base += __popcll(bal);
    }
    if (t == 0) *mc = base;
  }
}

// ------- W [1024][2048] -> transposed 3-way bf16 split (Q and K via z) -------
__global__ __launch_bounds__(256) void split_w(
    const float* __restrict__ Wq, const float* __restrict__ Wk,
    bf16* __restrict__ Tqh, bf16* __restrict__ Tqm, bf16* __restrict__ Tql,
    bf16* __restrict__ Tkh, bf16* __restrict__ Tkm, bf16* __restrict__ Tkl) {
  const float* W = blockIdx.z ? Wk : Wq;
  bf16* Th = blockIdx.z ? Tkh : Tqh;
  bf16* Tm = blockIdx.z ? Tkm : Tqm;
  bf16* Tl = blockIdx.z ? Tkl : Tql;
  __shared__ float tile[32][33];
  int n0 = blockIdx.x * 32, k0 = blockIdx.y * 32;
  int t = threadIdx.x, r = t >> 3, c4 = (t & 7) * 4;
  floatx4 v = *(const floatx4*)(W + (size_t)(k0 + r) * NP + n0 + c4);
  tile[r][c4 + 0] = v[0]; tile[r][c4 + 1] = v[1];
  tile[r][c4 + 2] = v[2]; tile[r][c4 + 3] = v[3];
  __syncthreads();
  bf16x4 hv, mv, lv;
  #pragma unroll
  for (int j = 0; j < 4; j++) {
    float x = tile[c4 + j][r];
    bf16 h = (bf16)x; float r1 = x - (float)h;
    bf16 m_ = (bf16)r1; float r2 = r1 - (float)m_;
    hv[j] = h; mv[j] = m_; lv[j] = (bf16)r2;
  }
  size_t base = (size_t)(n0 + r) * DM + k0 + c4;
  *(bf16x4*)(Th + base) = hv;
  *(bf16x4*)(Tm + base) = mv;
  *(bf16x4*)(Tl + base) = lv;
}

// ---- Q/K projection: 3-term split bf16 MFMA (6 products), fp32 acc; z=Q/K ---
__global__ __launch_bounds__(256) void proj_qk3(
    const float* __restrict__ X,
    const bf16* __restrict__ Qh_, const bf16* __restrict__ Qm_, const bf16* __restrict__ Ql_,
    const bf16* __restrict__ Kh_, const bf16* __restrict__ Km_, const bf16* __restrict__ Kl_,
    const float* __restrict__ bq, const float* __restrict__ bk,
    const int* __restrict__ midx, const int* __restrict__ mc,
    float* __restrict__ qf, float* __restrict__ kf,
    bf16* __restrict__ qbf, bf16* __restrict__ kbf) {
  int mcv = *mc;
  int ms = blockIdx.x * 128;
  if (mcv == 0 || ms >= mcv) return;
  int z = blockIdx.z;
  const bf16* WTh = z ? Kh_ : Qh_;
  const bf16* WTm = z ? Km_ : Qm_;
  const bf16* WTl = z ? Kl_ : Ql_;
  const float* bia = z ? bk : bq;
  float* outf = z ? kf : qf;
  bf16*  outb = z ? kbf : qbf;
  int ns = blockIdx.y * 128, head = blockIdx.y;
  __shared__ alignas(16) bf16 Ah[128][40], Am[128][40], Al[128][40];
  __shared__ alignas(16) bf16 Bh[128][40], Bm[128][40], Bl[128][40];
  int t = threadIdx.x, w = t >> 6, lane = t & 63, l15 = lane & 15, qd = lane >> 4;
  int wm = (w >> 1) * 64, wn = (w & 1) * 64;
  int amr = t >> 1, akb = (t & 1) * 16;
  int bnr = t >> 1, bkb = (t & 1) * 16;
  int cr = ms + amr;
  const float* xrow = X + (size_t)midx[cr < mcv ? cr : (mcv - 1)] * DM;
  const bf16* bhp = WTh + (size_t)(ns + bnr) * DM + bkb;
  const bf16* bmp = WTm + (size_t)(ns + bnr) * DM + bkb;
  const bf16* blp = WTl + (size_t)(ns + bnr) * DM + bkb;

  floatx4 acc[4][4];
  for (int i = 0; i < 4; i++)
    for (int j = 0; j < 4; j++) acc[i][j] = (floatx4){0.f, 0.f, 0.f, 0.f};

  for (int kt = 0; kt < DM; kt += 32) {
    floatx4 xa[4];
    #pragma unroll
    for (int u = 0; u < 4; u++)
      xa[u] = *(const floatx4*)(xrow + kt + akb + u * 4);
    bf16x8 wb[6];
    wb[0] = *(const bf16x8*)(bhp + kt);  wb[1] = *(const bf16x8*)(bhp + kt + 8);
    wb[2] = *(const bf16x8*)(bmp + kt);  wb[3] = *(const bf16x8*)(bmp + kt + 8);
    wb[4] = *(const bf16x8*)(blp + kt);  wb[5] = *(const bf16x8*)(blp + kt + 8);
    __syncthreads();
    bf16 ah8[16], am8[16], al8[16];
    #pragma unroll
    for (int u = 0; u < 4; u++)
      #pragma unroll
      for (int j = 0; j < 4; j++) {
        float v = xa[u][j];
        bf16 h = (bf16)v; float r1 = v - (float)h;
        bf16 m_ = (bf16)r1; float r2 = r1 - (float)m_;
        int e = u * 4 + j;
        ah8[e] = h; am8[e] = m_; al8[e] = (bf16)r2;
      }
    *(bf16x8*)&Ah[amr][akb]     = *(bf16x8*)&ah8[0];
    *(bf16x8*)&Ah[amr][akb + 8] = *(bf16x8*)&ah8[8];
    *(bf16x8*)&Am[amr][akb]     = *(bf16x8*)&am8[0];
    *(bf16x8*)&Am[amr][akb + 8] = *(bf16x8*)&am8[8];
    *(bf16x8*)&Al[amr][akb]     = *(bf16x8*)&al8[0];
    *(bf16x8*)&Al[amr][akb + 8] = *(bf16x8*)&al8[8];
    *(bf16x8*)&Bh[bnr][bkb]     = wb[0];
    *(bf16x8*)&Bh[bnr][bkb + 8] = wb[1];
    *(bf16x8*)&Bm[bnr][bkb]     = wb[2];
    *(bf16x8*)&Bm[bnr][bkb + 8] = wb[3];
    *(bf16x8*)&Bl[bnr][bkb]     = wb[4];
    *(bf16x8*)&Bl[bnr][bkb + 8] = wb[5];
    __syncthreads();
    bf16x8 fah[4], fam[4], fal[4], fbh[4], fbm[4], fbl[4];
    #pragma unroll
    for (int i = 0; i < 4; i++) {
      fah[i] = *(const bf16x8*)&Ah[wm + i * 16 + l15][qd * 8];
      fam[i] = *(const bf16x8*)&Am[wm + i * 16 + l15][qd * 8];
      fal[i] = *(const bf16x8*)&Al[wm + i * 16 + l15][qd * 8];
    }
    #pragma unroll
    for (int j = 0; j < 4; j++) {
      fbh[j] = *(const bf16x8*)&Bh[wn + j * 16 + l15][qd * 8];
      fbm[j] = *(const bf16x8*)&Bm[wn + j * 16 + l15][qd * 8];
      fbl[j] = *(const bf16x8*)&Bl[wn + j * 16 + l15][qd * 8];
    }
    #pragma unroll
    for (int i = 0; i < 4; i++)
      #pragma unroll
      for (int j = 0; j < 4; j++) {
        floatx4 a = acc[i][j];
        a = __builtin_amdgcn_mfma_f32_16x16x32_bf16(fal[i], fbh[j], a, 0, 0, 0);
        a = __builtin_amdgcn_mfma_f32_16x16x32_bf16(fah[i], fbl[j], a, 0, 0, 0);
        a = __builtin_amdgcn_mfma_f32_16x16x32_bf16(fam[i], fbm[j], a, 0, 0, 0);
        a = __builtin_amdgcn_mfma_f32_16x16x32_bf16(fam[i], fbh[j], a, 0, 0, 0);
        a = __builtin_amdgcn_mfma_f32_16x16x32_bf16(fah[i], fbm[j], a, 0, 0, 0);
        a = __builtin_amdgcn_mfma_f32_16x16x32_bf16(fah[i], fbh[j], a, 0, 0, 0);
        acc[i][j] = a;
      }
  }
  #pragma unroll
  for (int i = 0; i < 4; i++)
    #pragma unroll
    for (int j = 0; j < 4; j++) {
      int col = wn + j * 16 + l15;
      float bb = bia[ns + col];
      #pragma unroll
      for (int r = 0; r < 4; r++) {
        int row = ms + wm + i * 16 + qd * 4 + r;
        float v = acc[i][j][r] + bb;
        size_t idx = ((size_t)head * SEQ + row) * 128 + col;
        outf[idx] = v;
        outb[idx] = (bf16)v;
      }
    }
}

// -------- V projection via bf16 MFMA + fused column-sum (for the mean) ------
__global__ __launch_bounds__(256) void proj_v_mfma(
    const float* __restrict__ X, const float* __restrict__ W,
    const float* __restrict__ bia, float* __restrict__ out,
    float* __restrict__ sums) {
  __shared__ alignas(16) bf16 As[128][40];
  __shared__ alignas(16) bf16 Bs[128][40];
  __shared__ float colsum[128];
  int ms = blockIdx.x * 128, ns = blockIdx.y * 128;
  int t = threadIdx.x, w = t >> 6, lane = t & 63, l15 = lane & 15, qd = lane >> 4;
  int wm = (w >> 1) * 64, wn = (w & 1) * 64;
  int amr = t >> 1, akb = (t & 1) * 16;
  int bkr = t >> 3, bnb = (t & 7) * 16;
  if (t < 128) colsum[t] = 0.f;
  floatx4 acc[4][4];
  for (int i = 0; i < 4; i++)
    for (int j = 0; j < 4; j++) acc[i][j] = (floatx4){0.f, 0.f, 0.f, 0.f};

  for (int kt = 0; kt < DM; kt += 32) {
    floatx4 xa[4], wv[4];
    for (int u = 0; u < 4; u++)
      xa[u] = *(const floatx4*)(X + (size_t)(ms + amr) * DM + kt + akb + u * 4);
    for (int u = 0; u < 4; u++)
      wv[u] = *(const floatx4*)(W + (size_t)(kt + bkr) * NP + ns + bnb + u * 4);
    __syncthreads();
    {
      bf16x8 p0, p1;
      for (int j = 0; j < 4; j++) { p0[j] = (bf16)xa[0][j]; p0[4 + j] = (bf16)xa[1][j]; }
      for (int j = 0; j < 4; j++) { p1[j] = (bf16)xa[2][j]; p1[4 + j] = (bf16)xa[3][j]; }
      *(bf16x8*)&As[amr][akb]     = p0;
      *(bf16x8*)&As[amr][akb + 8] = p1;
    }
    for (int u = 0; u < 4; u++)
      for (int j = 0; j < 4; j++)
        Bs[bnb + u * 4 + j][bkr] = (bf16)wv[u][j];
    __syncthreads();
    bf16x8 af[4], bfr[4];
    for (int i = 0; i < 4; i++) af[i]  = *(const bf16x8*)&As[wm + i * 16 + l15][qd * 8];
    for (int j = 0; j < 4; j++) bfr[j] = *(const bf16x8*)&Bs[wn + j * 16 + l15][qd * 8];
    for (int i = 0; i < 4; i++)
      for (int j = 0; j < 4; j++)
        acc[i][j] = __builtin_amdgcn_mfma_f32_16x16x32_bf16(af[i], bfr[j], acc[i][j], 0, 0, 0);
  }
  float part[4] = {0.f, 0.f, 0.f, 0.f};
  for (int i = 0; i < 4; i++) {
    for (int j = 0; j < 4; j++) {
      int n = ns + wn + j * 16 + l15;
      float bb = bia[n];
      for (int r = 0; r < 4; r++) {
        int m = ms + wm + i * 16 + qd * 4 + r;
        float v = acc[i][j][r] + bb;
        out[(size_t)m * NP + n] = v;
        part[j] += v;
      }
    }
  }
  for (int j = 0; j < 4; j++)
    atomicAdd(&colsum[wn + j * 16 + l15], part[j]);
  __syncthreads();
  if (t < 128) atomicAdd(&sums[ns + t], colsum[t]);
}

// ------- S1: approx scores (bf16 MFMA), per-row global min ------------------
__global__ __launch_bounds__(256) void scores_min(
    const bf16* __restrict__ Qb, const bf16* __restrict__ Kb,
    const int* __restrict__ mc,
    unsigned* __restrict__ gmin) {
  int mcv = *mc;
  int h = blockIdx.x, s0 = blockIdx.y * 64, chunk = blockIdx.z;
  if (s0 >= mcv) return;
  int ntiles = (mcv + 63) >> 6;
  __shared__ float lmin[64][4];
  int t = threadIdx.x, w = t >> 6, lane = t & 63, l15 = lane & 15, qd = lane >> 4;
  const bf16* Qh = Qb + (size_t)h * SEQ * 128;
  const bf16* Kh = Kb + (size_t)h * SEQ * 128;
  bf16x8 af[4][4];
  for (int ksp = 0; ksp < 4; ksp++)
    for (int i = 0; i < 4; i++)
      af[ksp][i] = *(const bf16x8*)(Qh + (size_t)(s0 + i * 16 + l15) * 128 + ksp * 32 + qd * 8);
  float rmin[4][4];
  for (int i = 0; i < 4; i++)
    for (int r = 0; r < 4; r++) rmin[i][r] = INFINITY;

  for (int tt = chunk; tt < ntiles; tt += 8) {
    int t0 = tt * 64;
    floatx4 acc[4];
    for (int i = 0; i < 4; i++) acc[i] = (floatx4){0.f, 0.f, 0.f, 0.f};
    for (int ksp = 0; ksp < 4; ksp++) {
      bf16x8 bfr = *(const bf16x8*)(Kh + (size_t)(t0 + w * 16 + l15) * 128 + ksp * 32 + qd * 8);
      for (int i = 0; i < 4; i++)
        acc[i] = __builtin_amdgcn_mfma_f32_16x16x32_bf16(af[ksp][i], bfr, acc[i], 0, 0, 0);
    }
    bool okc = (t0 + w * 16 + l15) < mcv;
    for (int i = 0; i < 4; i++)
      for (int r = 0; r < 4; r++)
        rmin[i][r] = fminf(rmin[i][r], okc ? acc[i][r] : INFINITY);
  }
  for (int m = 1; m < 16; m <<= 1)
    for (int i = 0; i < 4; i++)
      for (int r = 0; r < 4; r++)
        rmin[i][r] = fminf(rmin[i][r], __shfl_xor(rmin[i][r], m));
  if (l15 == 0)
    for (int i = 0; i < 4; i++)
      for (int r = 0; r < 4; r++)
        lmin[i * 16 + qd * 4 + r][w] = rmin[i][r];
  __syncthreads();
  if (t < 64) {
    int row = s0 + t;
    if (row < mcv) {
      float cm = fminf(fminf(lmin[t][0], lmin[t][1]), fminf(lmin[t][2], lmin[t][3]));
      atomicMin(&gmin[h * 2048 + row], enc_f(cm));
    }
  }
}

// ------- S2: identical MFMA pass, pushes candidates vs gmin+MARGIN ----------
// Same instruction sequence as scores_min => bit-identical scores; any t with
// approx <= gmin + MARGIN is collected for exact fp64 rescoring.
__global__ __launch_bounds__(256) void scores_collect(
    const bf16* __restrict__ Qb, const bf16* __restrict__ Kb,
    const int* __restrict__ mc, const unsigned* __restrict__ gmin,
    unsigned* __restrict__ cand, int* __restrict__ gcount) {
  int mcv = *mc;
  int h = blockIdx.x, s0 = blockIdx.y * 64, chunk = blockIdx.z;
  if (s0 >= mcv) return;
  int ntiles = (mcv + 63) >> 6;
  __shared__ float fmin[64];
  int t = threadIdx.x, w = t >> 6, lane = t & 63, l15 = lane & 15, qd = lane >> 4;
  const bf16* Qh = Qb + (size_t)h * SEQ * 128;
  const bf16* Kh = Kb + (size_t)h * SEQ * 128;
  if (t < 64) {
    int row = s0 + t;
    fmin[t] = (row < mcv) ? dec_f(gmin[h * 2048 + row]) + MARGIN : -INFINITY;
  }
  bf16x8 af[4][4];
  for (int ksp = 0; ksp < 4; ksp++)
    for (int i = 0; i < 4; i++)
      af[ksp][i] = *(const bf16x8*)(Qh + (size_t)(s0 + i * 16 + l15) * 128 + ksp * 32 + qd * 8);
  __syncthreads();

  for (int tt = chunk; tt < ntiles; tt += 8) {
    int t0 = tt * 64;
    floatx4 acc[4];
    for (int i = 0; i < 4; i++) acc[i] = (floatx4){0.f, 0.f, 0.f, 0.f};
    for (int ksp = 0; ksp < 4; ksp++) {
      bf16x8 bfr = *(const bf16x8*)(Kh + (size_t)(t0 + w * 16 + l15) * 128 + ksp * 32 + qd * 8);
      for (int i = 0; i < 4; i++)
        acc[i] = __builtin_amdgcn_mfma_f32_16x16x32_bf16(af[ksp][i], bfr, acc[i], 0, 0, 0);
    }
    int tg = t0 + w * 16 + l15;
    if (tg < mcv) {
      for (int i = 0; i < 4; i++)
        for (int r = 0; r < 4; r++) {
          int rr = i * 16 + qd * 4 + r;
          if (acc[i][r] <= fmin[rr]) {
            int pos = atomicAdd(gcount, 1);
            if (pos < CAP)
              cand[pos] = ((unsigned)h << 22) | ((unsigned)(s0 + rr) << 11) | (unsigned)tg;
          }
        }
    }
  }
}

// ---------------- fp64 exact rescore (compacted rows), atomicMin key --------
__global__ __launch_bounds__(256) void rescore(
    const float* __restrict__ Q, const float* __restrict__ K,
    const int* __restrict__ midx,
    const unsigned* __restrict__ cand, const int* __restrict__ gcount,
    unsigned long long* __restrict__ keys) {
  int wid  = (blockIdx.x * 256 + threadIdx.x) >> 6;
  int lane = threadIdx.x & 63;
  int nw = gridDim.x * 4;
  int n = *gcount; if (n > CAP) n = CAP;
  for (int c = wid; c < n; c += nw) {
    unsigned u = cand[c];
    int h = u >> 22, cs = (u >> 11) & 2047, ct = u & 2047;
    floatx2 qv = *(const floatx2*)(Q + ((size_t)h * SEQ + cs) * 128 + lane * 2);
    floatx2 kv = *(const floatx2*)(K + ((size_t)h * SEQ + ct) * 128 + lane * 2);
    double d = (double)qv[0] * (double)kv[0] + (double)qv[1] * (double)kv[1];
    for (int off = 32; off; off >>= 1) d += __shfl_down(d, off);
    if (lane == 0) {
      int sorig = midx[cs], torig = midx[ct];
      long long b = __double_as_longlong(d);
      unsigned long long ub = (b >= 0) ? ((unsigned long long)b | 0x8000000000000000ULL)
                                       : ~(unsigned long long)b;
      unsigned long long key = (ub & ~2047ULL) | (unsigned long long)torig;
      atomicMin(&keys[(size_t)h * SEQ + sorig], key);
    }
  }
}

// ---------------- gather / mean, fp32 out ----------------
__global__ __launch_bounds__(256) void assemble(
    const float* __restrict__ V, const float* __restrict__ sums,
    const int* __restrict__ mask, const unsigned long long* __restrict__ keys,
    float* __restrict__ out) {
  int idx = blockIdx.x * 256 + threadIdx.x;
  int s = idx >> 11, n = idx & 2047, h = n >> 7;
  float val;
  if (mask[s]) {
    int tt = (int)(keys[(size_t)h * SEQ + s] & 2047ULL);
    val = V[(size_t)tt * NP + n];
  } else {
    val = sums[n] * (1.0f / 2048.0f);
  }
  out[idx] = val;
}

extern "C" void kernel_launch(void* const* d_in, const int* in_sizes, int n_in,
                              void* d_out, int out_size, void* d_ws, size_t ws_size,
                              hipStream_t stream) {
  (void)in_sizes; (void)n_in; (void)out_size; (void)ws_size;
  const float* X    = (const float*)d_in[0];
  const void*  mraw = d_in[1];
  const float* Wq   = (const float*)d_in[2];
  const float* bq   = (const float*)d_in[3];
  const float* Wk   = (const float*)d_in[4];
  const float* bk   = (const float*)d_in[5];
  const float* Wv   = (const float*)d_in[6];
  const float* bv   = (const float*)d_in[7];

  char* ws = (char*)d_ws;
  float* qf  = (float*)ws;                                  // 0..16MB
  float* kf  = (float*)(ws + ((size_t)16 << 20));           // 16..32MB
  bf16*  qbf = (bf16*) (ws + ((size_t)32 << 20));           // 32..40MB
  bf16*  kbf = (bf16*) (ws + ((size_t)40 << 20));           // 40..48MB
  // 48..72MB: W splits (dead after proj_qk3), then overlaid by vf + cand
  bf16* wqh = (bf16*)(ws + ((size_t)48 << 20));
  bf16* wqm = (bf16*)(ws + ((size_t)52 << 20));
  bf16* wql = (bf16*)(ws + ((size_t)56 << 20));
  bf16* wkh = (bf16*)(ws + ((size_t)60 << 20));
  bf16* wkm = (bf16*)(ws + ((size_t)64 << 20));
  bf16* wkl = (bf16*)(ws + ((size_t)68 << 20));
  float* vf = (float*)(ws + ((size_t)48 << 20));            // 16MB (after proj_qk3)
  unsigned* cand = (unsigned*)(ws + ((size_t)64 << 20));    // 4MB  (after proj_qk3)
  char* misc = ws + ((size_t)72 << 20);
  int*   maskw  = (int*)misc;                                   // 8KB
  int*   midx   = (int*)(misc + (8 << 10));                     // 8KB
  int*   mc     = (int*)(misc + (16 << 10));                    // 4B
  int*   gcount = (int*)(misc + (16 << 10) + 64);               // 4B
  int*   pcount = (int*)(misc + (16 << 10) + 128);              // 4B
  float* sums   = (float*)(misc + (32 << 10));                  // 8KB
  unsigned long long* keys = (unsigned long long*)(misc + (64 << 10));  // 256KB
  unsigned* gmin = (unsigned*)(misc + (320 << 10));             // 128KB
  float* out = (float*)d_out;

  mask_prep<<<33, 256, 0, stream>>>(mraw, maskw, midx, mc, gcount, pcount, sums, keys, gmin);
  split_w<<<dim3(64, 32, 2), 256, 0, stream>>>(Wq, Wk, wqh, wqm, wql, wkh, wkm, wkl);
  proj_qk3<<<dim3(16, 16, 2), 256, 0, stream>>>(X, wqh, wqm, wql, wkh, wkm, wkl,
                                                bq, bk, midx, mc, qf, kf, qbf, kbf);
  proj_v_mfma<<<dim3(16, 16), 256, 0, stream>>>(X, Wv, bv, vf, sums);
  scores_min<<<dim3(16, 32, 8), 256, 0, stream>>>(qbf, kbf, mc, gmin);
  scores_collect<<<dim3(16, 32, 8), 256, 0, stream>>>(qbf, kbf, mc, gmin, cand, gcount);
  rescore<<<512, 256, 0, stream>>>(qf, kf, midx, cand, gcount, keys);
  assemble<<<16384, 256, 0, stream>>>(vf, sums, maskw, keys, out);
}

// Round 11
// 485.346 us; speedup vs baseline: 2.0740x; 1.0461x over previous
//
#include <hip/hip_runtime.h>
#include <hip/hip_bf16.h>
#include <cfloat>
#include <math.h>

typedef __bf16 bf16;
typedef __bf16 bf16x4 __attribute__((ext_vector_type(4)));
typedef __bf16 bf16x8 __attribute__((ext_vector_type(8)));
typedef float  floatx4 __attribute__((ext_vector_type(4)));
typedef float  floatx2 __attribute__((ext_vector_type(2)));

#define SEQ 2048
#define DM  1024
#define NP  2048
#define CAP (1 << 20)
#define MARGIN 0.5f

__device__ __forceinline__ unsigned enc_f(float f) {
  unsigned b = __float_as_uint(f);
  return ((int)b >= 0) ? (b | 0x80000000u) : ~b;
}
__device__ __forceinline__ float dec_f(unsigned u) {
  return (u & 0x80000000u) ? __uint_as_float(u & 0x7fffffffu) : __uint_as_float(~u);
}

// ------- mask detect + compaction (block 0) + parallel inits (blocks 1..32) --
__global__ __launch_bounds__(256) void mask_prep(
    const void* __restrict__ mraw, int* __restrict__ maskw,
    int* __restrict__ midx, int* __restrict__ mc,
    int* __restrict__ gcount, float* __restrict__ sums,
    unsigned long long* __restrict__ keys, unsigned* __restrict__ gmin) {
  int t = threadIdx.x;
  if (blockIdx.x > 0) {
    int b = blockIdx.x - 1;                 // 0..31
    for (int j = 0; j < 4; j++) {
      int i = b * 1024 + j * 256 + t;
      keys[i] = ~0ULL;
      gmin[i] = 0xFFFFFFFFu;
    }
    if (b == 0) for (int i = t; i < 2048; i += 256) sums[i] = 0.f;
    return;
  }
  __shared__ int flags;
  __shared__ int lmask[2048];
  if (t == 0) { flags = 0; *gcount = 0; }
  __syncthreads();
  const unsigned short* u16 = (const unsigned short*)mraw;
  const unsigned* u32 = (const unsigned*)mraw;
  int f = 0;
  for (int i = t; i < 1024; i += 256) {
    unsigned short v = u16[i];
    if (v != 0 && v != 0x3F80u) f |= 1;
    if ((i & 1) == 0 && v == 0x3F80u) f |= 2;
  }
  for (int i = t; i < 512; i += 256)
    if (u32[i] > 1u) f |= 4;
  if (f) atomicOr(&flags, f);
  __syncthreads();
  int fl = flags;
  int mode;
  if (!(fl & 1)) mode = (fl & 2) ? 2 : 3;
  else           mode = (fl & 4) ? 1 : 0;
  for (int s = t; s < SEQ; s += 256) {
    int m;
    if (mode == 0)      m = (((const int*)mraw)[s] != 0);
    else if (mode == 1) m = (((const unsigned char*)mraw)[s] != 0);
    else if (mode == 2) m = (u16[s] != 0);
    else                m = (((const float*)mraw)[s] != 0.0f);
    maskw[s] = m; lmask[s] = m;
  }
  __syncthreads();
  if (t < 64) {
    int base = 0;
    for (int c = 0; c < 32; c++) {
      int s = c * 64 + t;
      bool m = lmask[s] != 0;
      unsigned long long bal = __ballot(m);
      if (m) midx[base + __popcll(bal & ((1ULL << t) - 1ULL))] = s;
      base += __popcll(bal);
    }
    if (t == 0) *mc = base;
  }
}

// ------- W [1024][2048] -> transposed 3-way bf16 split (Q and K via z) -------
__global__ __launch_bounds__(256) void split_w(
    const float* __restrict__ Wq, const float* __restrict__ Wk,
    bf16* __restrict__ Tqh, bf16* __restrict__ Tqm, bf16* __restrict__ Tql,
    bf16* __restrict__ Tkh, bf16* __restrict__ Tkm, bf16* __restrict__ Tkl) {
  const float* W = blockIdx.z ? Wk : Wq;
  bf16* Th = blockIdx.z ? Tkh : Tqh;
  bf16* Tm = blockIdx.z ? Tkm : Tqm;
  bf16* Tl = blockIdx.z ? Tkl : Tql;
  __shared__ float tile[32][33];
  int n0 = blockIdx.x * 32, k0 = blockIdx.y * 32;
  int t = threadIdx.x, r = t >> 3, c4 = (t & 7) * 4;
  floatx4 v = *(const floatx4*)(W + (size_t)(k0 + r) * NP + n0 + c4);
  tile[r][c4 + 0] = v[0]; tile[r][c4 + 1] = v[1];
  tile[r][c4 + 2] = v[2]; tile[r][c4 + 3] = v[3];
  __syncthreads();
  bf16x4 hv, mv, lv;
  #pragma unroll
  for (int j = 0; j < 4; j++) {
    float x = tile[c4 + j][r];
    bf16 h = (bf16)x; float r1 = x - (float)h;
    bf16 m_ = (bf16)r1; float r2 = r1 - (float)m_;
    hv[j] = h; mv[j] = m_; lv[j] = (bf16)r2;
  }
  size_t base = (size_t)(n0 + r) * DM + k0 + c4;
  *(bf16x4*)(Th + base) = hv;
  *(bf16x4*)(Tm + base) = mv;
  *(bf16x4*)(Tl + base) = lv;
}

// ---- Q/K projection: 3-term split bf16 MFMA (6 products), fp32 acc; z=Q/K ---
__global__ __launch_bounds__(256) void proj_qk3(
    const float* __restrict__ X,
    const bf16* __restrict__ Qh_, const bf16* __restrict__ Qm_, const bf16* __restrict__ Ql_,
    const bf16* __restrict__ Kh_, const bf16* __restrict__ Km_, const bf16* __restrict__ Kl_,
    const float* __restrict__ bq, const float* __restrict__ bk,
    const int* __restrict__ midx, const int* __restrict__ mc,
    float* __restrict__ qf, float* __restrict__ kf,
    bf16* __restrict__ qbf, bf16* __restrict__ kbf) {
  int mcv = *mc;
  int ms = blockIdx.x * 128;
  if (mcv == 0 || ms >= mcv) return;
  int z = blockIdx.z;
  const bf16* WTh = z ? Kh_ : Qh_;
  const bf16* WTm = z ? Km_ : Qm_;
  const bf16* WTl = z ? Kl_ : Ql_;
  const float* bia = z ? bk : bq;
  float* outf = z ? kf : qf;
  bf16*  outb = z ? kbf : qbf;
  int ns = blockIdx.y * 128, head = blockIdx.y;
  __shared__ alignas(16) bf16 Ah[128][40], Am[128][40], Al[128][40];
  __shared__ alignas(16) bf16 Bh[128][40], Bm[128][40], Bl[128][40];
  int t = threadIdx.x, w = t >> 6, lane = t & 63, l15 = lane & 15, qd = lane >> 4;
  int wm = (w >> 1) * 64, wn = (w & 1) * 64;
  int amr = t >> 1, akb = (t & 1) * 16;
  int bnr = t >> 1, bkb = (t & 1) * 16;
  int cr = ms + amr;
  const float* xrow = X + (size_t)midx[cr < mcv ? cr : (mcv - 1)] * DM;
  const bf16* bhp = WTh + (size_t)(ns + bnr) * DM + bkb;
  const bf16* bmp = WTm + (size_t)(ns + bnr) * DM + bkb;
  const bf16* blp = WTl + (size_t)(ns + bnr) * DM + bkb;

  floatx4 acc[4][4];
  for (int i = 0; i < 4; i++)
    for (int j = 0; j < 4; j++) acc[i][j] = (floatx4){0.f, 0.f, 0.f, 0.f};

  for (int kt = 0; kt < DM; kt += 32) {
    floatx4 xa[4];
    #pragma unroll
    for (int u = 0; u < 4; u++)
      xa[u] = *(const floatx4*)(xrow + kt + akb + u * 4);
    bf16x8 wb[6];
    wb[0] = *(const bf16x8*)(bhp + kt);  wb[1] = *(const bf16x8*)(bhp + kt + 8);
    wb[2] = *(const bf16x8*)(bmp + kt);  wb[3] = *(const bf16x8*)(bmp + kt + 8);
    wb[4] = *(const bf16x8*)(blp + kt);  wb[5] = *(const bf16x8*)(blp + kt + 8);
    __syncthreads();
    bf16 ah8[16], am8[16], al8[16];
    #pragma unroll
    for (int u = 0; u < 4; u++)
      #pragma unroll
      for (int j = 0; j < 4; j++) {
        float v = xa[u][j];
        bf16 h = (bf16)v; float r1 = v - (float)h;
        bf16 m_ = (bf16)r1; float r2 = r1 - (float)m_;
        int e = u * 4 + j;
        ah8[e] = h; am8[e] = m_; al8[e] = (bf16)r2;
      }
    *(bf16x8*)&Ah[amr][akb]     = *(bf16x8*)&ah8[0];
    *(bf16x8*)&Ah[amr][akb + 8] = *(bf16x8*)&ah8[8];
    *(bf16x8*)&Am[amr][akb]     = *(bf16x8*)&am8[0];
    *(bf16x8*)&Am[amr][akb + 8] = *(bf16x8*)&am8[8];
    *(bf16x8*)&Al[amr][akb]     = *(bf16x8*)&al8[0];
    *(bf16x8*)&Al[amr][akb + 8] = *(bf16x8*)&al8[8];
    *(bf16x8*)&Bh[bnr][bkb]     = wb[0];
    *(bf16x8*)&Bh[bnr][bkb + 8] = wb[1];
    *(bf16x8*)&Bm[bnr][bkb]     = wb[2];
    *(bf16x8*)&Bm[bnr][bkb + 8] = wb[3];
    *(bf16x8*)&Bl[bnr][bkb]     = wb[4];
    *(bf16x8*)&Bl[bnr][bkb + 8] = wb[5];
    __syncthreads();
    bf16x8 fah[4], fam[4], fal[4], fbh[4], fbm[4], fbl[4];
    #pragma unroll
    for (int i = 0; i < 4; i++) {
      fah[i] = *(const bf16x8*)&Ah[wm + i * 16 + l15][qd * 8];
      fam[i] = *(const bf16x8*)&Am[wm + i * 16 + l15][qd * 8];
      fal[i] = *(const bf16x8*)&Al[wm + i * 16 + l15][qd * 8];
    }
    #pragma unroll
    for (int j = 0; j < 4; j++) {
      fbh[j] = *(const bf16x8*)&Bh[wn + j * 16 + l15][qd * 8];
      fbm[j] = *(const bf16x8*)&Bm[wn + j * 16 + l15][qd * 8];
      fbl[j] = *(const bf16x8*)&Bl[wn + j * 16 + l15][qd * 8];
    }
    #pragma unroll
    for (int i = 0; i < 4; i++)
      #pragma unroll
      for (int j = 0; j < 4; j++) {
        floatx4 a = acc[i][j];
        a = __builtin_amdgcn_mfma_f32_16x16x32_bf16(fal[i], fbh[j], a, 0, 0, 0);
        a = __builtin_amdgcn_mfma_f32_16x16x32_bf16(fah[i], fbl[j], a, 0, 0, 0);
        a = __builtin_amdgcn_mfma_f32_16x16x32_bf16(fam[i], fbm[j], a, 0, 0, 0);
        a = __builtin_amdgcn_mfma_f32_16x16x32_bf16(fam[i], fbh[j], a, 0, 0, 0);
        a = __builtin_amdgcn_mfma_f32_16x16x32_bf16(fah[i], fbm[j], a, 0, 0, 0);
        a = __builtin_amdgcn_mfma_f32_16x16x32_bf16(fah[i], fbh[j], a, 0, 0, 0);
        acc[i][j] = a;
      }
  }
  #pragma unroll
  for (int i = 0; i < 4; i++)
    #pragma unroll
    for (int j = 0; j < 4; j++) {
      int col = wn + j * 16 + l15;
      float bb = bia[ns + col];
      #pragma unroll
      for (int r = 0; r < 4; r++) {
        int row = ms + wm + i * 16 + qd * 4 + r;
        float v = acc[i][j][r] + bb;
        size_t idx = ((size_t)head * SEQ + row) * 128 + col;
        outf[idx] = v;
        outb[idx] = (bf16)v;
      }
    }
}

// -------- V projection via bf16 MFMA + fused column-sum (for the mean) ------
__global__ __launch_bounds__(256) void proj_v_mfma(
    const float* __restrict__ X, const float* __restrict__ W,
    const float* __restrict__ bia, float* __restrict__ out,
    float* __restrict__ sums) {
  __shared__ alignas(16) bf16 As[128][40];
  __shared__ alignas(16) bf16 Bs[128][40];
  __shared__ float colsum[128];
  int ms = blockIdx.x * 128, ns = blockIdx.y * 128;
  int t = threadIdx.x, w = t >> 6, lane = t & 63, l15 = lane & 15, qd = lane >> 4;
  int wm = (w >> 1) * 64, wn = (w & 1) * 64;
  int amr = t >> 1, akb = (t & 1) * 16;
  int bkr = t >> 3, bnb = (t & 7) * 16;
  if (t < 128) colsum[t] = 0.f;
  floatx4 acc[4][4];
  for (int i = 0; i < 4; i++)
    for (int j = 0; j < 4; j++) acc[i][j] = (floatx4){0.f, 0.f, 0.f, 0.f};

  for (int kt = 0; kt < DM; kt += 32) {
    floatx4 xa[4], wv[4];
    for (int u = 0; u < 4; u++)
      xa[u] = *(const floatx4*)(X + (size_t)(ms + amr) * DM + kt + akb + u * 4);
    for (int u = 0; u < 4; u++)
      wv[u] = *(const floatx4*)(W + (size_t)(kt + bkr) * NP + ns + bnb + u * 4);
    __syncthreads();
    {
      bf16x8 p0, p1;
      for (int j = 0; j < 4; j++) { p0[j] = (bf16)xa[0][j]; p0[4 + j] = (bf16)xa[1][j]; }
      for (int j = 0; j < 4; j++) { p1[j] = (bf16)xa[2][j]; p1[4 + j] = (bf16)xa[3][j]; }
      *(bf16x8*)&As[amr][akb]     = p0;
      *(bf16x8*)&As[amr][akb + 8] = p1;
    }
    for (int u = 0; u < 4; u++)
      for (int j = 0; j < 4; j++)
        Bs[bnb + u * 4 + j][bkr] = (bf16)wv[u][j];
    __syncthreads();
    bf16x8 af[4], bfr[4];
    for (int i = 0; i < 4; i++) af[i]  = *(const bf16x8*)&As[wm + i * 16 + l15][qd * 8];
    for (int j = 0; j < 4; j++) bfr[j] = *(const bf16x8*)&Bs[wn + j * 16 + l15][qd * 8];
    for (int i = 0; i < 4; i++)
      for (int j = 0; j < 4; j++)
        acc[i][j] = __builtin_amdgcn_mfma_f32_16x16x32_bf16(af[i], bfr[j], acc[i][j], 0, 0, 0);
  }
  float part[4] = {0.f, 0.f, 0.f, 0.f};
  for (int i = 0; i < 4; i++) {
    for (int j = 0; j < 4; j++) {
      int n = ns + wn + j * 16 + l15;
      float bb = bia[n];
      for (int r = 0; r < 4; r++) {
        int m = ms + wm + i * 16 + qd * 4 + r;
        float v = acc[i][j][r] + bb;
        out[(size_t)m * NP + n] = v;
        part[j] += v;
      }
    }
  }
  for (int j = 0; j < 4; j++)
    atomicAdd(&colsum[wn + j * 16 + l15], part[j]);
  __syncthreads();
  if (t < 128) atomicAdd(&sums[ns + t], colsum[t]);
}

// ------- S1: approx scores (bf16 MFMA), LDS-staged K, per-row global min ----
// Q tile staged once (coalesced), K tiles staged per iteration with register
// prefetch of the next tile overlapping MFMA. Scores bit-identical to S2.
__global__ __launch_bounds__(256) void scores_min(
    const bf16* __restrict__ Qb, const bf16* __restrict__ Kb,
    const int* __restrict__ mc,
    unsigned* __restrict__ gmin) {
  int mcv = *mc;
  int h = blockIdx.x, s0 = blockIdx.y * 64;
  if (s0 >= mcv) return;
  int ntiles = (mcv + 63) >> 6;
  int half = (ntiles + 1) >> 1;
  int tbeg = blockIdx.z * half;
  int tend = ntiles < tbeg + half ? ntiles : tbeg + half;
  __shared__ alignas(16) bf16 qs[64][136];
  __shared__ alignas(16) bf16 ks[64][136];
  __shared__ float lmin[64][4];
  int t = threadIdx.x, w = t >> 6, lane = t & 63, l15 = lane & 15, qd = lane >> 4;
  const bf16* Qh = Qb + (size_t)h * SEQ * 128;
  const bf16* Kh = Kb + (size_t)h * SEQ * 128;
  int sr = t >> 4, sseg = (t & 15) * 8;   // staging: 16B chunk per thread, x4
  #pragma unroll
  for (int j = 0; j < 4; j++)
    *(bf16x8*)&qs[sr + j * 16][sseg] = *(const bf16x8*)(Qh + (size_t)(s0 + sr + j * 16) * 128 + sseg);
  bf16x8 pre[4];
  #pragma unroll
  for (int j = 0; j < 4; j++)
    pre[j] = *(const bf16x8*)(Kh + (size_t)(tbeg * 64 + sr + j * 16) * 128 + sseg);
  __syncthreads();
  bf16x8 af[4][4];
  for (int ksp = 0; ksp < 4; ksp++)
    for (int i = 0; i < 4; i++)
      af[ksp][i] = *(const bf16x8*)&qs[i * 16 + l15][ksp * 32 + qd * 8];
  float rmin[4][4];
  for (int i = 0; i < 4; i++)
    for (int r = 0; r < 4; r++) rmin[i][r] = INFINITY;

  for (int tt = tbeg; tt < tend; tt++) {
    __syncthreads();
    #pragma unroll
    for (int j = 0; j < 4; j++)
      *(bf16x8*)&ks[sr + j * 16][sseg] = pre[j];
    __syncthreads();
    if (tt + 1 < tend) {
      #pragma unroll
      for (int j = 0; j < 4; j++)
        pre[j] = *(const bf16x8*)(Kh + (size_t)((tt + 1) * 64 + sr + j * 16) * 128 + sseg);
    }
    floatx4 acc[4];
    for (int i = 0; i < 4; i++) acc[i] = (floatx4){0.f, 0.f, 0.f, 0.f};
    for (int ksp = 0; ksp < 4; ksp++) {
      bf16x8 bfr = *(const bf16x8*)&ks[w * 16 + l15][ksp * 32 + qd * 8];
      for (int i = 0; i < 4; i++)
        acc[i] = __builtin_amdgcn_mfma_f32_16x16x32_bf16(af[ksp][i], bfr, acc[i], 0, 0, 0);
    }
    bool okc = (tt * 64 + w * 16 + l15) < mcv;
    for (int i = 0; i < 4; i++)
      for (int r = 0; r < 4; r++)
        rmin[i][r] = fminf(rmin[i][r], okc ? acc[i][r] : INFINITY);
  }
  for (int m = 1; m < 16; m <<= 1)
    for (int i = 0; i < 4; i++)
      for (int r = 0; r < 4; r++)
        rmin[i][r] = fminf(rmin[i][r], __shfl_xor(rmin[i][r], m));
  if (l15 == 0)
    for (int i = 0; i < 4; i++)
      for (int r = 0; r < 4; r++)
        lmin[i * 16 + qd * 4 + r][w] = rmin[i][r];
  __syncthreads();
  if (t < 64) {
    int row = s0 + t;
    if (row < mcv) {
      float cm = fminf(fminf(lmin[t][0], lmin[t][1]), fminf(lmin[t][2], lmin[t][3]));
      atomicMin(&gmin[h * 2048 + row], enc_f(cm));
    }
  }
}

// ------- S2: identical LDS-staged MFMA pass, pushes candidates vs gmin+MARGIN
__global__ __launch_bounds__(256) void scores_collect(
    const bf16* __restrict__ Qb, const bf16* __restrict__ Kb,
    const int* __restrict__ mc, const unsigned* __restrict__ gmin,
    unsigned* __restrict__ cand, int* __restrict__ gcount) {
  int mcv = *mc;
  int h = blockIdx.x, s0 = blockIdx.y * 64;
  if (s0 >= mcv) return;
  int ntiles = (mcv + 63) >> 6;
  int half = (ntiles + 1) >> 1;
  int tbeg = blockIdx.z * half;
  int tend = ntiles < tbeg + half ? ntiles : tbeg + half;
  __shared__ alignas(16) bf16 qs[64][136];
  __shared__ alignas(16) bf16 ks[64][136];
  __shared__ float fmin[64];
  int t = threadIdx.x, w = t >> 6, lane = t & 63, l15 = lane & 15, qd = lane >> 4;
  const bf16* Qh = Qb + (size_t)h * SEQ * 128;
  const bf16* Kh = Kb + (size_t)h * SEQ * 128;
  int sr = t >> 4, sseg = (t & 15) * 8;
  #pragma unroll
  for (int j = 0; j < 4; j++)
    *(bf16x8*)&qs[sr + j * 16][sseg] = *(const bf16x8*)(Qh + (size_t)(s0 + sr + j * 16) * 128 + sseg);
  bf16x8 pre[4];
  #pragma unroll
  for (int j = 0; j < 4; j++)
    pre[j] = *(const bf16x8*)(Kh + (size_t)(tbeg * 64 + sr + j * 16) * 128 + sseg);
  if (t < 64) {
    int row = s0 + t;
    fmin[t] = (row < mcv) ? dec_f(gmin[h * 2048 + row]) + MARGIN : -INFINITY;
  }
  __syncthreads();
  bf16x8 af[4][4];
  for (int ksp = 0; ksp < 4; ksp++)
    for (int i = 0; i < 4; i++)
      af[ksp][i] = *(const bf16x8*)&qs[i * 16 + l15][ksp * 32 + qd * 8];
  float fm[4][4];
  for (int i = 0; i < 4; i++)
    for (int r = 0; r < 4; r++) fm[i][r] = fmin[i * 16 + qd * 4 + r];

  for (int tt = tbeg; tt < tend; tt++) {
    __syncthreads();
    #pragma unroll
    for (int j = 0; j < 4; j++)
      *(bf16x8*)&ks[sr + j * 16][sseg] = pre[j];
    __syncthreads();
    if (tt + 1 < tend) {
      #pragma unroll
      for (int j = 0; j < 4; j++)
        pre[j] = *(const bf16x8*)(Kh + (size_t)((tt + 1) * 64 + sr + j * 16) * 128 + sseg);
    }
    floatx4 acc[4];
    for (int i = 0; i < 4; i++) acc[i] = (floatx4){0.f, 0.f, 0.f, 0.f};
    for (int ksp = 0; ksp < 4; ksp++) {
      bf16x8 bfr = *(const bf16x8*)&ks[w * 16 + l15][ksp * 32 + qd * 8];
      for (int i = 0; i < 4; i++)
        acc[i] = __builtin_amdgcn_mfma_f32_16x16x32_bf16(af[ksp][i], bfr, acc[i], 0, 0, 0);
    }
    int tg = tt * 64 + w * 16 + l15;
    if (tg < mcv) {
      for (int i = 0; i < 4; i++)
        for (int r = 0; r < 4; r++) {
          if (acc[i][r] <= fm[i][r]) {
            int rr = i * 16 + qd * 4 + r;
            int pos = atomicAdd(gcount, 1);
            if (pos < CAP)
              cand[pos] = ((unsigned)h << 22) | ((unsigned)(s0 + rr) << 11) | (unsigned)tg;
          }
        }
    }
  }
}

// ---------------- fp64 exact rescore (compacted rows), atomicMin key --------
__global__ __launch_bounds__(256) void rescore(
    const float* __restrict__ Q, const float* __restrict__ K,
    const int* __restrict__ midx,
    const unsigned* __restrict__ cand, const int* __restrict__ gcount,
    unsigned long long* __restrict__ keys) {
  int wid  = (blockIdx.x * 256 + threadIdx.x) >> 6;
  int lane = threadIdx.x & 63;
  int nw = gridDim.x * 4;
  int n = *gcount; if (n > CAP) n = CAP;
  for (int c = wid; c < n; c += nw) {
    unsigned u = cand[c];
    int h = u >> 22, cs = (u >> 11) & 2047, ct = u & 2047;
    floatx2 qv = *(const floatx2*)(Q + ((size_t)h * SEQ + cs) * 128 + lane * 2);
    floatx2 kv = *(const floatx2*)(K + ((size_t)h * SEQ + ct) * 128 + lane * 2);
    double d = (double)qv[0] * (double)kv[0] + (double)qv[1] * (double)kv[1];
    for (int off = 32; off; off >>= 1) d += __shfl_down(d, off);
    if (lane == 0) {
      int sorig = midx[cs], torig = midx[ct];
      long long b = __double_as_longlong(d);
      unsigned long long ub = (b >= 0) ? ((unsigned long long)b | 0x8000000000000000ULL)
                                       : ~(unsigned long long)b;
      unsigned long long key = (ub & ~2047ULL) | (unsigned long long)torig;
      atomicMin(&keys[(size_t)h * SEQ + sorig], key);
    }
  }
}

// ---------------- gather / mean, fp32 out ----------------
__global__ __launch_bounds__(256) void assemble(
    const float* __restrict__ V, const float* __restrict__ sums,
    const int* __restrict__ mask, const unsigned long long* __restrict__ keys,
    float* __restrict__ out) {
  int idx = blockIdx.x * 256 + threadIdx.x;
  int s = idx >> 11, n = idx & 2047, h = n >> 7;
  float val;
  if (mask[s]) {
    int tt = (int)(keys[(size_t)h * SEQ + s] & 2047ULL);
    val = V[(size_t)tt * NP + n];
  } else {
    val = sums[n] * (1.0f / 2048.0f);
  }
  out[idx] = val;
}

extern "C" void kernel_launch(void* const* d_in, const int* in_sizes, int n_in,
                              void* d_out, int out_size, void* d_ws, size_t ws_size,
                              hipStream_t stream) {
  (void)in_sizes; (void)n_in; (void)out_size; (void)ws_size;
  const float* X    = (const float*)d_in[0];
  const void*  mraw = d_in[1];
  const float* Wq   = (const float*)d_in[2];
  const float* bq   = (const float*)d_in[3];
  const float* Wk   = (const float*)d_in[4];
  const float* bk   = (const float*)d_in[5];
  const float* Wv   = (const float*)d_in[6];
  const float* bv   = (const float*)d_in[7];

  char* ws = (char*)d_ws;
  float* qf  = (float*)ws;                                  // 0..16MB
  float* kf  = (float*)(ws + ((size_t)16 << 20));           // 16..32MB
  bf16*  qbf = (bf16*) (ws + ((size_t)32 << 20));           // 32..40MB
  bf16*  kbf = (bf16*) (ws + ((size_t)40 << 20));           // 40..48MB
  // 48..72MB: W splits (dead after proj_qk3), then overlaid by vf + cand
  bf16* wqh = (bf16*)(ws + ((size_t)48 << 20));
  bf16* wqm = (bf16*)(ws + ((size_t)52 << 20));
  bf16* wql = (bf16*)(ws + ((size_t)56 << 20));
  bf16* wkh = (bf16*)(ws + ((size_t)60 << 20));
  bf16* wkm = (bf16*)(ws + ((size_t)64 << 20));
  bf16* wkl = (bf16*)(ws + ((size_t)68 << 20));
  float* vf = (float*)(ws + ((size_t)48 << 20));            // 16MB (after proj_qk3)
  unsigned* cand = (unsigned*)(ws + ((size_t)64 << 20));    // 4MB  (after proj_qk3)
  char* misc = ws + ((size_t)72 << 20);
  int*   maskw  = (int*)misc;                                   // 8KB
  int*   midx   = (int*)(misc + (8 << 10));                     // 8KB
  int*   mc     = (int*)(misc + (16 << 10));                    // 4B
  int*   gcount = (int*)(misc + (16 << 10) + 64);               // 4B
  float* sums   = (float*)(misc + (32 << 10));                  // 8KB
  unsigned long long* keys = (unsigned long long*)(misc + (64 << 10));  // 256KB
  unsigned* gmin = (unsigned*)(misc + (320 << 10));             // 128KB
  float* out = (float*)d_out;

  mask_prep<<<33, 256, 0, stream>>>(mraw, maskw, midx, mc, gcount, sums, keys, gmin);
  split_w<<<dim3(64, 32, 2), 256, 0, stream>>>(Wq, Wk, wqh, wqm, wql, wkh, wkm, wkl);
  proj_qk3<<<dim3(16, 16, 2), 256, 0, stream>>>(X, wqh, wqm, wql, wkh, wkm, wkl,
                                                bq, bk, midx, mc, qf, kf, qbf, kbf);
  proj_v_mfma<<<dim3(16, 16), 256, 0, stream>>>(X, Wv, bv, vf, sums);
  scores_min<<<dim3(16, 32, 2), 256, 0, stream>>>(qbf, kbf, mc, gmin);
  scores_collect<<<dim3(16, 32, 2), 256, 0, stream>>>(qbf, kbf, mc, gmin, cand, gcount);
  rescore<<<512, 256, 0, stream>>>(qf, kf, midx, cand, gcount, keys);
  assemble<<<16384, 256, 0, stream>>>(vf, sums, maskw, keys, out);
}